// Round 9
// baseline (2479.919 us; speedup 1.0000x reference)
//
#include <hip/hip_runtime.h>
#include <cstdint>
#include <cstddef>

constexpr int Tn = 12, Bn = 16, Nn = 1024, Hn = 64, Ln = 2;
constexpr int ROWS = Bn * Nn;                 // 16384
constexpr int TOT  = Tn * Bn * Nn;            // 196608
constexpr int HALF = TOT / 2;
constexpr size_t HSZ = (size_t)Bn * Nn * Hn;  // 1048576 floats
constexpr size_t MB = 1048576;

#define DEVFN __device__ __forceinline__

typedef __attribute__((ext_vector_type(4))) float f32x4;
typedef __attribute__((ext_vector_type(4))) int   i32x4;
typedef __attribute__((ext_vector_type(8))) __bf16 bf16x8;
typedef unsigned short ushort_t;

// weight-plane offsets (elements) inside WH/WL ([n][k] row layouts)
constexpr size_t WOFF_P2 = 98304;    // [n:64][k:256]   Wp2
constexpr size_t WOFF_D1 = 114688;   // [n:256][k:128]  Wd1
constexpr size_t WOFF_D2 = 147456;   // [n:64][k:256]   Wd2
constexpr size_t WTOT    = 163840;
// WT tile planes (1KB tiles [lm:16][kin:32]): PZ 4dl*8nt*4kt, PC 4dl*4nt*4kt
constexpr size_t WT_PC  = 65536;
constexpr size_t WTTOT  = 98304;

// ---------------------------------------------------------------------------
DEVFN ushort_t f2bf_rne(float f) {
  uint32_t u = __float_as_uint(f);
  uint32_t r = u + 0x7FFFu + ((u >> 16) & 1u);
  return (ushort_t)(r >> 16);
}
DEVFN float bf2f(ushort_t h) { return __uint_as_float(((uint32_t)h) << 16); }

DEVFN void split8(const float* f, bf16x8& h8, bf16x8& l8) {
  alignas(16) ushort_t hs[8], ls[8];
#pragma unroll
  for (int j = 0; j < 8; ++j) {
    ushort_t h = f2bf_rne(f[j]);
    hs[j] = h;
    ls[j] = f2bf_rne(f[j] - bf2f(h));
  }
  h8 = *reinterpret_cast<bf16x8*>(hs);
  l8 = *reinterpret_cast<bf16x8*>(ls);
}

DEVFN f32x4 mm3(bf16x8 ah, bf16x8 al, bf16x8 bh, bf16x8 bl, f32x4 c) {
  c = __builtin_amdgcn_mfma_f32_16x16x32_bf16(ah, bh, c, 0, 0, 0);
  c = __builtin_amdgcn_mfma_f32_16x16x32_bf16(ah, bl, c, 0, 0, 0);
  c = __builtin_amdgcn_mfma_f32_16x16x32_bf16(al, bh, c, 0, 0, 0);
  return c;
}

DEVFN bf16x8 ld16(const ushort_t* p) { return *reinterpret_cast<const bf16x8*>(p); }

DEVFN void ld8f(const float* p, float* out) {
  float4 v0 = *reinterpret_cast<const float4*>(p);
  float4 v1 = *reinterpret_cast<const float4*>(p + 4);
  out[0] = v0.x; out[1] = v0.y; out[2] = v0.z; out[3] = v0.w;
  out[4] = v1.x; out[5] = v1.y; out[6] = v1.z; out[7] = v1.w;
}

DEVFN void async16(const void* g, void* l) {
  __builtin_amdgcn_global_load_lds(
      (const __attribute__((address_space(1))) uint32_t*)g,
      (__attribute__((address_space(3))) uint32_t*)l, 16, 0, 0);
}

DEVFN void quant_i8(float v, int& b1, int& b0) {
  int i = __float2int_rn(v * 4096.0f);
  i = max(-32768, min(32639, i));
  b1 = (i + 128) >> 8;
  b0 = i - (b1 << 8);
}

DEVFN void quantpack(const float* v, uint32_t& p1, uint32_t& p0) {
  p1 = 0; p0 = 0;
#pragma unroll
  for (int r = 0; r < 4; ++r) {
    int a, b;
    quant_i8(v[r], a, b);
    p1 |= ((uint32_t)(uint8_t)(char)a) << (8 * r);
    p0 |= ((uint32_t)(uint8_t)(char)b) << (8 * r);
  }
}

// ---------------------------------------------------------------------------
// threefry2x32 (key 0,42) + XLA-exact normal
// ---------------------------------------------------------------------------
DEVFN uint32_t rotl32(uint32_t v, int d) { return (v << d) | (v >> (32 - d)); }

DEVFN void threefry_0_42(uint32_t& x0, uint32_t& x1) {
  const uint32_t k0 = 0u, k1 = 42u, k2 = k0 ^ k1 ^ 0x1BD11BDAu;
  x0 += k0; x1 += k1;
#define TFR(r) { x0 += x1; x1 = rotl32(x1, r); x1 ^= x0; }
  TFR(13) TFR(15) TFR(26) TFR(6)
  x0 += k1; x1 += k2 + 1u;
  TFR(17) TFR(29) TFR(16) TFR(24)
  x0 += k2; x1 += k0 + 2u;
  TFR(13) TFR(15) TFR(26) TFR(6)
  x0 += k0; x1 += k1 + 3u;
  TFR(17) TFR(29) TFR(16) TFR(24)
  x0 += k1; x1 += k2 + 4u;
  TFR(13) TFR(15) TFR(26) TFR(6)
  x0 += k2; x1 += k0 + 5u;
#undef TFR
}

DEVFN float erfinv32(float x) {
  float w = -log1pf(-x * x);
  float p;
  if (w < 5.0f) {
    w = w - 2.5f;
    p = 2.81022636e-08f;
    p = fmaf(p, w, 3.43273939e-07f);
    p = fmaf(p, w, -3.5233877e-06f);
    p = fmaf(p, w, -4.39150654e-06f);
    p = fmaf(p, w, 0.00021858087f);
    p = fmaf(p, w, -0.00125372503f);
    p = fmaf(p, w, -0.00417768164f);
    p = fmaf(p, w, 0.246640727f);
    p = fmaf(p, w, 1.50140941f);
  } else {
    w = sqrtf(w) - 3.0f;
    p = -0.000200214257f;
    p = fmaf(p, w, 0.000100950558f);
    p = fmaf(p, w, 0.00134934322f);
    p = fmaf(p, w, -0.00367342844f);
    p = fmaf(p, w, 0.00573950773f);
    p = fmaf(p, w, -0.0076224613f);
    p = fmaf(p, w, 0.00943887047f);
    p = fmaf(p, w, 1.00167406f);
    p = fmaf(p, w, 2.83297682f);
  }
  return p * x;
}

DEVFN float bits_to_normal(uint32_t bits) {
  float f = __uint_as_float((bits >> 9) | 0x3f800000u) - 1.0f;
  const float lo = -0.99999994f;
  float u = fmaf(f, 2.0f, lo);
  u = fmaxf(lo, u);
  return 1.41421356237f * erfinv32(u);
}

__global__ __launch_bounds__(256) void seq_kernel(const float* __restrict__ inputs,
                                                  float* __restrict__ s0) {
  int i = blockIdx.x * 256 + threadIdx.x;
  if (i >= HALF) return;
  uint32_t x0 = (uint32_t)i, x1 = (uint32_t)(i + HALF);
  threefry_0_42(x0, x1);
  s0[i]        = inputs[i]        + 0.01f * bits_to_normal(x0);
  s0[i + HALF] = inputs[i + HALF] + 0.01f * bits_to_normal(x1);
}

DEVFN float sigmoidf_(float x) { return 1.0f / (1.0f + expf(-x)); }

// ---------------------------------------------------------------------------
__global__ __launch_bounds__(256) void adjsplit_kernel(const float* __restrict__ adj,
                                                       char* __restrict__ d1,
                                                       char* __restrict__ d0) {
  int i = blockIdx.x * 256 + threadIdx.x;
  int A = __float2int_rn(adj[i] * 16777216.0f);
  int a1 = (A + 128) >> 8;
  int a0 = A - (a1 << 8);
  d1[i] = (char)a1;
  d0[i] = (char)a0;
}

// ---------------------------------------------------------------------------
// wprep: [n][k] bf16 hi/lo planes for proj/dec GEMMs
// ---------------------------------------------------------------------------
__global__ __launch_bounds__(256) void wprep_kernel(
    const float* __restrict__ Wp2, const float* __restrict__ Wd1, const float* __restrict__ Wd2,
    ushort_t* __restrict__ WH, ushort_t* __restrict__ WL)
{
  size_t i = (size_t)blockIdx.x * 256 + threadIdx.x + WOFF_P2;
  if (i >= WTOT) return;
  float v;
  if (i < WOFF_D1) {                          // P2 [n:64][k:256]
    size_t j = i - WOFF_P2;
    int n = j >> 8, k = j & 255;
    v = Wp2[k * 64 + n];
  } else if (i < WOFF_D2) {                   // D1 [n:256][k:128]
    size_t j = i - WOFF_D1;
    int n = j >> 7, k = j & 127;
    v = Wd1[k * 256 + n];
  } else {                                    // D2 [n:64][k:256]
    size_t j = i - WOFF_D2;
    int n = j >> 8, k = j & 255;
    v = Wd2[k * 64 + n];
  }
  ushort_t h = f2bf_rne(v);
  WH[i] = h;
  WL[i] = f2bf_rne(v - bf2f(h));
}

// ---------------------------------------------------------------------------
// wtprep: gate weights as wave-contiguous 1KB tiles [lm:16][kin:32]
// PZ: [dl][nt:8][kt2:4] over [Wz|Wr]; PC: [dl][nt:4][kt2:4] over Wc
// ---------------------------------------------------------------------------
__global__ __launch_bounds__(256) void wtprep_kernel(
    const float* __restrict__ WzF, const float* __restrict__ WrF, const float* __restrict__ WcF,
    const float* __restrict__ WzR, const float* __restrict__ WrR, const float* __restrict__ WcR,
    ushort_t* __restrict__ WTH, ushort_t* __restrict__ WTL)
{
  size_t i = (size_t)blockIdx.x * 256 + threadIdx.x;
  if (i >= WTTOT) return;
  float v;
  if (i < WT_PC) {
    int dl = i >> 14, r = i & 16383;
    int nt = r >> 11, kt2 = (r >> 9) & 3, e = r & 511;
    int lm = e >> 5, kin = e & 31;
    int d = dl >> 1, l = dl & 1;
    int n = nt * 16 + lm, k = kt2 * 32 + kin;
    const float* W = (n < 64) ? (d ? WzR : WzF) : (d ? WrR : WrF);
    v = W[l * 8192 + k * 64 + (n & 63)];
  } else {
    size_t j = i - WT_PC;
    int dl = j >> 13, r = j & 8191;
    int nt = r >> 11, kt2 = (r >> 9) & 3, e = r & 511;
    int lm = e >> 5, kin = e & 31;
    int d = dl >> 1, l = dl & 1;
    int n = nt * 16 + lm, k = kt2 * 32 + kin;
    const float* W = d ? WcR : WcF;
    v = W[l * 8192 + k * 64 + n];
  }
  ushort_t h = f2bf_rne(v);
  WTH[i] = h;
  WTL[i] = f2bf_rne(v - bf2f(h));
}

// ---------------------------------------------------------------------------
// proj: x = relu(s0*W0+s1*W1+bp1) @ Wp2 + bp2 -> XT digit planes
// ---------------------------------------------------------------------------
__global__ __launch_bounds__(256) void proj_mfma(
    const float* __restrict__ s0g, const float* __restrict__ s1g,
    const float* __restrict__ Wp1, const float* __restrict__ bp1,
    const float* __restrict__ bp2,
    const ushort_t* __restrict__ WH, const ushort_t* __restrict__ WL,
    char* __restrict__ XT1, char* __restrict__ XT0)
{
  __shared__ float W0[256], W1[256], Bb[256], SS0[256], SS1[256];
  const int tid = threadIdx.x;
  const int row0 = blockIdx.x * 256;
  W0[tid] = Wp1[tid];
  W1[tid] = Wp1[256 + tid];
  Bb[tid] = bp1[tid];
  SS0[tid] = s0g[row0 + tid];
  SS1[tid] = s1g[row0 + tid];
  __syncthreads();

  const int lane = tid & 63, wave = tid >> 6;
  const int lm = lane & 15, q8 = (lane >> 4) * 8;
  const ushort_t* P2H = WH + WOFF_P2;
  const ushort_t* P2L = WL + WOFF_P2;

  float sv0[4], sv1[4];
#pragma unroll
  for (int ti = 0; ti < 4; ++ti) {
    sv0[ti] = SS0[wave * 64 + ti * 16 + lm];
    sv1[ti] = SS1[wave * 64 + ti * 16 + lm];
  }

  f32x4 acc[4][4];
#pragma unroll
  for (int i = 0; i < 4; ++i)
#pragma unroll
    for (int j = 0; j < 4; ++j) acc[i][j] = (f32x4)0.0f;

  for (int kt = 0; kt < 8; ++kt) {
    const int kc = kt * 32 + q8;
    bf16x8 bh[4], bl[4];
#pragma unroll
    for (int tj = 0; tj < 4; ++tj) {
      bh[tj] = ld16(P2H + (size_t)(tj * 16 + lm) * 256 + kc);
      bl[tj] = ld16(P2L + (size_t)(tj * 16 + lm) * 256 + kc);
    }
    float w08[8], w18[8], bb8[8];
#pragma unroll
    for (int j = 0; j < 8; ++j) { w08[j] = W0[kc + j]; w18[j] = W1[kc + j]; bb8[j] = Bb[kc + j]; }
#pragma unroll
    for (int ti = 0; ti < 4; ++ti) {
      float a8[8];
#pragma unroll
      for (int j = 0; j < 8; ++j)
        a8[j] = fmaxf(fmaf(sv0[ti], w08[j], fmaf(sv1[ti], w18[j], bb8[j])), 0.0f);
      bf16x8 ah, al;
      split8(a8, ah, al);
#pragma unroll
      for (int tj = 0; tj < 4; ++tj) acc[ti][tj] = mm3(ah, al, bh[tj], bl[tj], acc[ti][tj]);
    }
  }

  const int rq = (lane >> 4) * 4;
  const int rowbase = row0 + wave * 64;
#pragma unroll
  for (int ti = 0; ti < 4; ++ti)
#pragma unroll
    for (int tj = 0; tj < 4; ++tj) {
      const int col = tj * 16 + lm;
      const float bv = bp2[col];
      float v4[4];
#pragma unroll
      for (int r = 0; r < 4; ++r) v4[r] = acc[ti][tj][r] + bv;
      uint32_t p1, p0;
      quantpack(v4, p1, p0);
      const int row = rowbase + ti * 16 + rq;
      const int t = row >> 14, b = (row >> 10) & 15, m = row & 1023;
      const size_t adr = (size_t)t * MB + (size_t)b * 65536 + (size_t)col * 1024 + m;
      *reinterpret_cast<uint32_t*>(XT1 + adr) = p1;
      *reinterpret_cast<uint32_t*>(XT0 + adr) = p0;
    }
}

// ---------------------------------------------------------------------------
// conv_fused<PHASE>: agg = adj @ [x|h'] (i8, K=1024), epilogue agg @ W + gates.
// Block 32n x 128feat, 256 thr, grid (16=b, 32=ntile, 2=dir) -> 1024 blocks.
// LDS: dbuf 2 x 20.5KB; single-pass epilogue with wave-tile W loads.
// ---------------------------------------------------------------------------
template<int PHASE>
__global__ __launch_bounds__(256) void conv_fused(
    const char* __restrict__ adj1, const char* __restrict__ adj0,
    const char* __restrict__ x0p1, const char* __restrict__ x0p0,
    const char* __restrict__ x1p1, const char* __restrict__ x1p0,
    const char* __restrict__ h0p1, const char* __restrict__ h0p0,
    const char* __restrict__ h1p1, const char* __restrict__ h1p0,
    const ushort_t* __restrict__ WTH, const ushort_t* __restrict__ WTL, int l,
    const float* __restrict__ b0F, const float* __restrict__ b0R,
    const float* __restrict__ b1F, const float* __restrict__ b1R,
    float* __restrict__ Z, float* __restrict__ Hbuf,
    char* __restrict__ out1, char* __restrict__ out0)
{
  constexpr int A0OFF = 2048, B1OFF = 4096, B0OFF = 12288, BUF = 20480;
  __shared__ __align__(16) char SM[2 * BUF];     // 40 KB

  const int tid = threadIdx.x;
  const int b   = blockIdx.x;                    // id%8 == b%8 -> XCD-local b
  const int n0  = blockIdx.y * 32;
  const int dir = blockIdx.z;
  const char* xp1 = dir ? x1p1 : x0p1;
  const char* xp0 = dir ? x1p0 : x0p0;
  const char* hp1 = dir ? h1p1 : h0p1;
  const char* hp0 = dir ? h1p0 : h0p0;
  const int lane = tid & 63, wave = tid >> 6;
  const int sr = lane & 15, sq = lane >> 4;
  const int lm = lane & 15, q8 = (lane >> 4) * 8, rq4 = (lane >> 4) * 4;
  const int rowg = wave & 1, colg = wave >> 1;

  // 20 x 1KB transfers per iter; wave w takes t = w, w+4, ..., w+16
  const char* tsrc[5];
  int tdst[5];
#pragma unroll
  for (int i = 0; i < 5; ++i) {
    const int t = wave + i * 4;
    const char* base; int dst;
    if (t < 2)       { const int g = t;      base = adj1 + (size_t)(n0 + g * 16 + sr) * 1024; dst = g * 1024; }
    else if (t < 4)  { const int g = t - 2;  base = adj0 + (size_t)(n0 + g * 16 + sr) * 1024; dst = A0OFF + g * 1024; }
    else if (t < 8)  { const int g = t - 4;  base = xp1 + (size_t)b * 65536 + (size_t)(g * 16 + sr) * 1024; dst = B1OFF + g * 1024; }
    else if (t < 12) { const int g = t - 8;  base = hp1 + (size_t)b * 65536 + (size_t)(g * 16 + sr) * 1024; dst = B1OFF + 4096 + g * 1024; }
    else if (t < 16) { const int g = t - 12; base = xp0 + (size_t)b * 65536 + (size_t)(g * 16 + sr) * 1024; dst = B0OFF + g * 1024; }
    else             { const int g = t - 16; base = hp0 + (size_t)b * 65536 + (size_t)(g * 16 + sr) * 1024; dst = B0OFF + 4096 + g * 1024; }
    tsrc[i] = base + sq * 16;
    tdst[i] = dst;
  }

#define STG(bi, it)                                                \
  {                                                                \
    char* _L = SM + (bi) * BUF;                                    \
    _Pragma("unroll")                                              \
    for (int i = 0; i < 5; ++i)                                    \
      async16(tsrc[i] + (it) * 64, _L + tdst[i]);                  \
  }

  i32x4 acc1[4], accm[4];
#pragma unroll
  for (int j = 0; j < 4; ++j) { acc1[j] = (i32x4)0; accm[j] = (i32x4)0; }

  STG(0, 0)
  for (int kt = 0; kt < 16; ++kt) {
    __syncthreads();
    if (kt + 1 < 16) STG((kt + 1) & 1, kt + 1)
    const char* L = SM + (kt & 1) * BUF;
    i32x4 a1 = *reinterpret_cast<const i32x4*>(L + rowg * 1024 + lane * 16);
    i32x4 a0 = *reinterpret_cast<const i32x4*>(L + A0OFF + rowg * 1024 + lane * 16);
#pragma unroll
    for (int tj = 0; tj < 4; ++tj) {
      const int g = colg * 4 + tj;
      i32x4 b1 = *reinterpret_cast<const i32x4*>(L + B1OFF + g * 1024 + lane * 16);
      i32x4 b0 = *reinterpret_cast<const i32x4*>(L + B0OFF + g * 1024 + lane * 16);
      acc1[tj] = __builtin_amdgcn_mfma_i32_16x16x64_i8(a1, b1, acc1[tj], 0, 0, 0);
      accm[tj] = __builtin_amdgcn_mfma_i32_16x16x64_i8(a1, b0, accm[tj], 0, 0, 0);
      accm[tj] = __builtin_amdgcn_mfma_i32_16x16x64_i8(a0, b1, accm[tj], 0, 0, 0);
    }
  }
#undef STG

  // ---------------- epilogue --------------------------------------------
  const float S1 = 0x1p-20f, Sm = 0x1p-28f;
  float* Tf = (float*)SM;                        // [32][132] = 16.9 KB
  constexpr int TFS = 132;
  constexpr int TJ2 = (PHASE == 0) ? 4 : 2;
  const int colb = (PHASE == 0) ? colg * 64 : colg * 32;
  const int dl = dir * 2 + l;
  const ushort_t* WBH = (PHASE == 0) ? WTH + (size_t)dl * 16384
                                     : WTH + WT_PC + (size_t)dl * 8192;
  const ushort_t* WBL = (PHASE == 0) ? WTL + (size_t)dl * 16384
                                     : WTL + WT_PC + (size_t)dl * 8192;
  const float* bz = dir ? b0R : b0F;
  const float* br = dir ? b1R : b1F;
  float* zst = Z + (size_t)dir * ((size_t)ROWS * 64);
  float* hb = Hbuf + (size_t)dl * HSZ;
  char* o1 = (PHASE == 0) ? out1 + (size_t)dir * MB : out1 + (size_t)dl * MB;
  char* o0 = (PHASE == 0) ? out0 + (size_t)dir * MB : out0 + (size_t)dl * MB;

  __syncthreads();                               // main-loop LDS reads done
#pragma unroll
  for (int tj = 0; tj < 4; ++tj)
#pragma unroll
    for (int r = 0; r < 4; ++r)
      Tf[(rowg * 16 + rq4 + r) * TFS + colg * 64 + tj * 16 + lm] =
          (float)acc1[tj][r] * S1 + (float)accm[tj][r] * Sm;
  __syncthreads();

  f32x4 a2[TJ2];
#pragma unroll
  for (int j = 0; j < TJ2; ++j) a2[j] = (f32x4)0.0f;
#pragma unroll
  for (int kt2 = 0; kt2 < 4; ++kt2) {
    const int k0 = kt2 * 32 + q8;
    bf16x8 wh[TJ2], wl[TJ2];
#pragma unroll
    for (int j = 0; j < TJ2; ++j) {
      const int nt = (colb >> 4) + j;
      const size_t off = (size_t)(nt * 4 + kt2) * 512 + lm * 32 + q8;
      wh[j] = ld16(WBH + off);
      wl[j] = ld16(WBL + off);
    }
    float a8[8];
    ld8f(&Tf[(rowg * 16 + lm) * TFS + k0], a8);
    bf16x8 ah, al;
    split8(a8, ah, al);
#pragma unroll
    for (int j = 0; j < TJ2; ++j) a2[j] = mm3(ah, al, wh[j], wl[j], a2[j]);
  }

  const size_t grow0 = (size_t)b * 1024 + n0 + rowg * 16 + rq4;
  const int m0 = n0 + rowg * 16 + rq4;
  if (PHASE == 0) {
    if (colg == 0) {                   // z gate (cols 0-63)
#pragma unroll
      for (int j = 0; j < TJ2; ++j) {
        const int c = j * 16 + lm;
        const float bv = bz[c];
#pragma unroll
        for (int r = 0; r < 4; ++r)
          zst[(grow0 + r) * 64 + c] = sigmoidf_(a2[j][r] + bv);
      }
    } else {                           // r gate -> rh digits (cols 64-127)
#pragma unroll
      for (int j = 0; j < TJ2; ++j) {
        const int c = j * 16 + lm;
        const float bv = br[c];
        float rv[4];
#pragma unroll
        for (int r = 0; r < 4; ++r)
          rv[r] = sigmoidf_(a2[j][r] + bv) * hb[(grow0 + r) * 64 + c];
        uint32_t p1, p0;
        quantpack(rv, p1, p0);
        const size_t adr = (size_t)b * 65536 + (size_t)c * 1024 + m0;
        *reinterpret_cast<uint32_t*>(o1 + adr) = p1;
        *reinterpret_cast<uint32_t*>(o0 + adr) = p0;
      }
    }
  } else {
#pragma unroll
    for (int j = 0; j < TJ2; ++j) {
      const int c = colb + j * 16 + lm;
      const float bv = bz[c];          // bc
      float hv4[4];
#pragma unroll
      for (int r = 0; r < 4; ++r) {
        const size_t idx = (grow0 + r) * 64 + c;
        const float cc = tanhf(a2[j][r] + bv);
        const float zv = zst[idx];
        const float hn = zv * hb[idx] + (1.0f - zv) * cc;
        hb[idx] = hn;
        hv4[r] = hn;
      }
      uint32_t p1, p0;
      quantpack(hv4, p1, p0);
      const size_t adr = (size_t)b * 65536 + (size_t)c * 1024 + m0;
      *reinterpret_cast<uint32_t*>(o1 + adr) = p1;
      *reinterpret_cast<uint32_t*>(o0 + adr) = p0;
    }
  }
}

// ---------------------------------------------------------------------------
// dec1: D1[row][256] = relu(concat(hid_f,hid_r)[row] @ Wd1 + bd1)
// ---------------------------------------------------------------------------
__global__ __launch_bounds__(256) void dec1_mfma(
    const float* __restrict__ Hws,
    const ushort_t* __restrict__ WH, const ushort_t* __restrict__ WL,
    const float* __restrict__ bd1,
    float* __restrict__ D1)
{
  const int tid = threadIdx.x;
  const int row0 = blockIdx.x * 128;
  const int cb   = blockIdx.y * 128;
  const int l  = row0 >> 14;
  const int ri0 = row0 & 16383;
  const float* Hf = Hws + (size_t)(0 * 2 + l) * HSZ;
  const float* Hr = Hws + (size_t)(1 * 2 + l) * HSZ;
  const ushort_t* BH = WH + WOFF_D1;
  const ushort_t* BL = WL + WOFF_D1;

  const int lane = tid & 63, wave = tid >> 6;
  const int wr = (wave >> 1) * 64, wc = (wave & 1) * 64;
  const int lm = lane & 15, q8 = (lane >> 4) * 8;

  f32x4 acc[4][4];
#pragma unroll
  for (int i = 0; i < 4; ++i)
#pragma unroll
    for (int j = 0; j < 4; ++j) acc[i][j] = (f32x4)0.0f;

#pragma unroll
  for (int kt = 0; kt < 4; ++kt) {
    const int k0 = kt * 32 + q8;
    bf16x8 bh[4], bl[4];
#pragma unroll
    for (int tj = 0; tj < 4; ++tj) {
      const size_t off = (size_t)(cb + wc + tj * 16 + lm) * 128 + k0;
      bh[tj] = ld16(BH + off);
      bl[tj] = ld16(BL + off);
    }
#pragma unroll
    for (int ti = 0; ti < 4; ++ti) {
      const int ri = ri0 + wr + ti * 16 + lm;
      const float* src = (k0 < 64) ? (Hf + (size_t)ri * 64 + k0)
                                   : (Hr + (size_t)ri * 64 + (k0 - 64));
      float a8[8];
      ld8f(src, a8);
      bf16x8 ah, al;
      split8(a8, ah, al);
#pragma unroll
      for (int tj = 0; tj < 4; ++tj) acc[ti][tj] = mm3(ah, al, bh[tj], bl[tj], acc[ti][tj]);
    }
  }

  const int rq = (lane >> 4) * 4;
#pragma unroll
  for (int ti = 0; ti < 4; ++ti)
#pragma unroll
    for (int tj = 0; tj < 4; ++tj) {
      const int col = cb + wc + tj * 16 + lm;
      const float bv = bd1[col];
#pragma unroll
      for (int r = 0; r < 4; ++r) {
        const size_t row = row0 + wr + ti * 16 + rq + r;
        D1[row * 256 + col] = fmaxf(acc[ti][tj][r] + bv, 0.0f);
      }
    }
}

// ---------------------------------------------------------------------------
// dec2: out[row][64] = D1[row] @ Wd2 + bd2
// ---------------------------------------------------------------------------
__global__ __launch_bounds__(256) void dec2_mfma(
    const float* __restrict__ D1,
    const ushort_t* __restrict__ WH, const ushort_t* __restrict__ WL,
    const float* __restrict__ bd2,
    float* __restrict__ out)
{
  const int tid = threadIdx.x;
  const int row0 = blockIdx.x * 256;
  const ushort_t* BH = WH + WOFF_D2;
  const ushort_t* BL = WL + WOFF_D2;

  const int lane = tid & 63, wave = tid >> 6;
  const int wr = wave * 64;
  const int lm = lane & 15, q8 = (lane >> 4) * 8;

  f32x4 acc[4][4];
#pragma unroll
  for (int i = 0; i < 4; ++i)
#pragma unroll
    for (int j = 0; j < 4; ++j) acc[i][j] = (f32x4)0.0f;

#pragma unroll
  for (int kt = 0; kt < 8; ++kt) {
    const int k0 = kt * 32 + q8;
    bf16x8 bh[4], bl[4];
#pragma unroll
    for (int tj = 0; tj < 4; ++tj) {
      const size_t off = (size_t)(tj * 16 + lm) * 256 + k0;
      bh[tj] = ld16(BH + off);
      bl[tj] = ld16(BL + off);
    }
#pragma unroll
    for (int ti = 0; ti < 4; ++ti) {
      const size_t row = row0 + wr + ti * 16 + lm;
      float a8[8];
      ld8f(D1 + row * 256 + k0, a8);
      bf16x8 ah, al;
      split8(a8, ah, al);
#pragma unroll
      for (int tj = 0; tj < 4; ++tj) acc[ti][tj] = mm3(ah, al, bh[tj], bl[tj], acc[ti][tj]);
    }
  }

  const int rq = (lane >> 4) * 4;
#pragma unroll
  for (int ti = 0; ti < 4; ++ti)
#pragma unroll
    for (int tj = 0; tj < 4; ++tj) {
      const int col = tj * 16 + lm;
      const float bv = bd2[col];
#pragma unroll
      for (int r = 0; r < 4; ++r) {
        const size_t row = row0 + wr + ti * 16 + rq + r;
        out[row * 64 + col] = acc[ti][tj][r] + bv;
      }
    }
}

// ---------------------------------------------------------------------------
// Host driver
// ---------------------------------------------------------------------------
extern "C" void kernel_launch(void* const* d_in, const int* in_sizes, int n_in,
                              void* d_out, int out_size, void* d_ws, size_t ws_size,
                              hipStream_t stream)
{
  (void)in_sizes; (void)n_in; (void)out_size; (void)ws_size;
  const float* inputs = (const float*)d_in[0];
  const float* mask   = (const float*)d_in[1];
  const float* adj    = (const float*)d_in[2];
  const float* Wp1    = (const float*)d_in[3];
  const float* bp1    = (const float*)d_in[4];
  const float* Wp2    = (const float*)d_in[5];
  const float* bp2    = (const float*)d_in[6];
  const float* Wz_f   = (const float*)d_in[7];
  const float* Wr_f   = (const float*)d_in[8];
  const float* Wc_f   = (const float*)d_in[9];
  const float* bz_f   = (const float*)d_in[10];
  const float* br_f   = (const float*)d_in[11];
  const float* bc_f   = (const float*)d_in[12];
  const float* Wz_r   = (const float*)d_in[13];
  const float* Wr_r   = (const float*)d_in[14];
  const float* Wc_r   = (const float*)d_in[15];
  const float* bz_r   = (const float*)d_in[16];
  const float* br_r   = (const float*)d_in[17];
  const float* bc_r   = (const float*)d_in[18];
  const float* Wd1    = (const float*)d_in[19];
  const float* bd1    = (const float*)d_in[20];
  const float* Wd2    = (const float*)d_in[21];
  const float* bd2    = (const float*)d_in[22];

  float* ws = (float*)d_ws;
  float* S0 = ws;                                   // TOT
  float* H  = S0 + TOT;                             // 4*HSZ [dir*2+l]
  float* Z  = H + 4 * HSZ;                          // 2*HSZ
  char* ADJ1 = (char*)(Z + 2 * HSZ);                // 1 MB
  char* ADJ0 = ADJ1 + MB;                           // 1 MB
  ushort_t* WH = (ushort_t*)(ADJ0 + MB);
  ushort_t* WL = WH + WTOT;
  ushort_t* WTH = WL + WTOT;
  ushort_t* WTL = WTH + WTTOT;
  char* XT1 = (char*)(WTL + WTTOT);                 // 12 MB [t][b][64][1024]
  char* XT0 = XT1 + 12 * MB;                        // 12 MB
  char* HT1 = XT0 + 12 * MB;                        // 4 MB  [dir*2+l][b][64][1024]
  char* HT0 = HT1 + 4 * MB;                         // 4 MB
  char* RT1 = HT0 + 4 * MB;                         // 2 MB  [dir][b][64][1024]
  char* RT0 = RT1 + 2 * MB;                         // 2 MB
  float* D1 = (float*)XT1;                          // 32 MB alias (post-loop)

  hipMemsetAsync(H, 0, 4 * HSZ * sizeof(float), stream);
  hipMemsetAsync(HT1, 0, 8 * MB, stream);           // HT1+HT0 contiguous

  seq_kernel<<<dim3((HALF + 255) / 256), 256, 0, stream>>>(inputs, S0);
  wprep_kernel<<<dim3((int)((WTOT - WOFF_P2 + 255) / 256)), 256, 0, stream>>>(
      Wp2, Wd1, Wd2, WH, WL);
  wtprep_kernel<<<dim3((int)((WTTOT + 255) / 256)), 256, 0, stream>>>(
      Wz_f, Wr_f, Wc_f, Wz_r, Wr_r, Wc_r, WTH, WTL);
  adjsplit_kernel<<<dim3(4096), 256, 0, stream>>>(adj, ADJ1, ADJ0);
  proj_mfma<<<dim3(TOT / 256), 256, 0, stream>>>(S0, mask, Wp1, bp1, bp2, WH, WL, XT1, XT0);

  for (int t = 0; t < Tn; ++t) {
    for (int l = 0; l < Ln; ++l) {
      const char* x01 = (l == 0) ? XT1 + (size_t)t * MB        : HT1 + 0 * MB;
      const char* x00 = (l == 0) ? XT0 + (size_t)t * MB        : HT0 + 0 * MB;
      const char* x11 = (l == 0) ? XT1 + (size_t)(11 - t) * MB : HT1 + 2 * MB;
      const char* x10 = (l == 0) ? XT0 + (size_t)(11 - t) * MB : HT0 + 2 * MB;

      conv_fused<0><<<dim3(16, 32, 2), 256, 0, stream>>>(
          ADJ1, ADJ0, x01, x00, x11, x10,
          HT1 + (size_t)(0 * 2 + l) * MB, HT0 + (size_t)(0 * 2 + l) * MB,
          HT1 + (size_t)(1 * 2 + l) * MB, HT0 + (size_t)(1 * 2 + l) * MB,
          WTH, WTL, l,
          bz_f + l * 64, bz_r + l * 64, br_f + l * 64, br_r + l * 64,
          Z, H, RT1, RT0);

      conv_fused<1><<<dim3(16, 32, 2), 256, 0, stream>>>(
          ADJ1, ADJ0, x01, x00, x11, x10,
          RT1, RT0, RT1 + MB, RT0 + MB,
          WTH, WTL, l,
          bc_f + l * 64, bc_r + l * 64, bc_f + l * 64, bc_r + l * 64,
          Z, H, HT1, HT0);
    }
  }

  dec1_mfma<<<dim3(256, 2), 256, 0, stream>>>(H, WH, WL, bd1, D1);
  dec2_mfma<<<dim3(128), 256, 0, stream>>>(D1, WH, WL, bd2, (float*)d_out);
}

// Round 10
// 1587.278 us; speedup vs baseline: 1.5624x; 1.5624x over previous
//
#include <hip/hip_runtime.h>
#include <cstdint>
#include <cstddef>

constexpr int Tn = 12, Bn = 16, Nn = 1024, Hn = 64, Ln = 2;
constexpr int ROWS = Bn * Nn;                 // 16384
constexpr int TOT  = Tn * Bn * Nn;            // 196608
constexpr int HALF = TOT / 2;
constexpr size_t HSZ = (size_t)Bn * Nn * Hn;  // 1048576 floats
constexpr size_t MB = 1048576;

#define DEVFN __device__ __forceinline__

typedef __attribute__((ext_vector_type(4))) float f32x4;
typedef __attribute__((ext_vector_type(4))) int   i32x4;
typedef __attribute__((ext_vector_type(8))) __bf16 bf16x8;
typedef unsigned short ushort_t;

// weight-plane offsets (elements) inside WH/WL (bf16 hi/lo)
constexpr size_t WOFF_PZ = 0;        // [d][l][n:128][k:128]  prez B
constexpr size_t WOFF_PC = 65536;    // [d][l][n:64][k:128]   prec B
constexpr size_t WOFF_P2 = 98304;    // [n:64][k:256]         Wp2
constexpr size_t WOFF_D1 = 114688;   // [n:256][k:128]        Wd1
constexpr size_t WOFF_D2 = 147456;   // [n:64][k:256]         Wd2
constexpr size_t WTOT    = 163840;

// ---------------------------------------------------------------------------
DEVFN ushort_t f2bf_rne(float f) {
  uint32_t u = __float_as_uint(f);
  uint32_t r = u + 0x7FFFu + ((u >> 16) & 1u);
  return (ushort_t)(r >> 16);
}
DEVFN float bf2f(ushort_t h) { return __uint_as_float(((uint32_t)h) << 16); }

DEVFN void split8(const float* f, bf16x8& h8, bf16x8& l8) {
  alignas(16) ushort_t hs[8], ls[8];
#pragma unroll
  for (int j = 0; j < 8; ++j) {
    ushort_t h = f2bf_rne(f[j]);
    hs[j] = h;
    ls[j] = f2bf_rne(f[j] - bf2f(h));
  }
  h8 = *reinterpret_cast<bf16x8*>(hs);
  l8 = *reinterpret_cast<bf16x8*>(ls);
}

DEVFN f32x4 mm3(bf16x8 ah, bf16x8 al, bf16x8 bh, bf16x8 bl, f32x4 c) {
  c = __builtin_amdgcn_mfma_f32_16x16x32_bf16(ah, bh, c, 0, 0, 0);
  c = __builtin_amdgcn_mfma_f32_16x16x32_bf16(ah, bl, c, 0, 0, 0);
  c = __builtin_amdgcn_mfma_f32_16x16x32_bf16(al, bh, c, 0, 0, 0);
  return c;
}

DEVFN bf16x8 ld16(const ushort_t* p) { return *reinterpret_cast<const bf16x8*>(p); }

DEVFN void ld8f(const float* p, float* out) {
  float4 v0 = *reinterpret_cast<const float4*>(p);
  float4 v1 = *reinterpret_cast<const float4*>(p + 4);
  out[0] = v0.x; out[1] = v0.y; out[2] = v0.z; out[3] = v0.w;
  out[4] = v1.x; out[5] = v1.y; out[6] = v1.z; out[7] = v1.w;
}

DEVFN void async16(const void* g, void* l) {
  __builtin_amdgcn_global_load_lds(
      (const __attribute__((address_space(1))) uint32_t*)g,
      (__attribute__((address_space(3))) uint32_t*)l, 16, 0, 0);
}

// i8 fixed point digits, scale 2^-12
DEVFN void quant_i8(float v, char& b1, char& b0) {
  int i = __float2int_rn(v * 4096.0f);
  i = max(-32768, min(32639, i));
  int d1 = (i + 128) >> 8;
  int d0 = i - (d1 << 8);
  b1 = (char)d1; b0 = (char)d0;
}

// tiled i8 plane addressing: within a 16-row group plane (16 KB per group):
//   addr = (mc=m>>6)*1024 + ((m>>4)&3)*256 + (row&15)*16 + (m&15)
DEVFN size_t tiladdr(int m) { return (size_t)(m >> 6) * 1024 + (size_t)((m >> 4) & 3) * 256 + (m & 15); }

// ---------------------------------------------------------------------------
// threefry2x32 (key 0,42) + XLA-exact normal
// ---------------------------------------------------------------------------
DEVFN uint32_t rotl32(uint32_t v, int d) { return (v << d) | (v >> (32 - d)); }

DEVFN void threefry_0_42(uint32_t& x0, uint32_t& x1) {
  const uint32_t k0 = 0u, k1 = 42u, k2 = k0 ^ k1 ^ 0x1BD11BDAu;
  x0 += k0; x1 += k1;
#define TFR(r) { x0 += x1; x1 = rotl32(x1, r); x1 ^= x0; }
  TFR(13) TFR(15) TFR(26) TFR(6)
  x0 += k1; x1 += k2 + 1u;
  TFR(17) TFR(29) TFR(16) TFR(24)
  x0 += k2; x1 += k0 + 2u;
  TFR(13) TFR(15) TFR(26) TFR(6)
  x0 += k0; x1 += k1 + 3u;
  TFR(17) TFR(29) TFR(16) TFR(24)
  x0 += k1; x1 += k2 + 4u;
  TFR(13) TFR(15) TFR(26) TFR(6)
  x0 += k2; x1 += k0 + 5u;
#undef TFR
}

DEVFN float erfinv32(float x) {
  float w = -log1pf(-x * x);
  float p;
  if (w < 5.0f) {
    w = w - 2.5f;
    p = 2.81022636e-08f;
    p = fmaf(p, w, 3.43273939e-07f);
    p = fmaf(p, w, -3.5233877e-06f);
    p = fmaf(p, w, -4.39150654e-06f);
    p = fmaf(p, w, 0.00021858087f);
    p = fmaf(p, w, -0.00125372503f);
    p = fmaf(p, w, -0.00417768164f);
    p = fmaf(p, w, 0.246640727f);
    p = fmaf(p, w, 1.50140941f);
  } else {
    w = sqrtf(w) - 3.0f;
    p = -0.000200214257f;
    p = fmaf(p, w, 0.000100950558f);
    p = fmaf(p, w, 0.00134934322f);
    p = fmaf(p, w, -0.00367342844f);
    p = fmaf(p, w, 0.00573950773f);
    p = fmaf(p, w, -0.0076224613f);
    p = fmaf(p, w, 0.00943887047f);
    p = fmaf(p, w, 1.00167406f);
    p = fmaf(p, w, 2.83297682f);
  }
  return p * x;
}

DEVFN float bits_to_normal(uint32_t bits) {
  float f = __uint_as_float((bits >> 9) | 0x3f800000u) - 1.0f;
  const float lo = -0.99999994f;
  float u = fmaf(f, 2.0f, lo);
  u = fmaxf(lo, u);
  return 1.41421356237f * erfinv32(u);
}

__global__ __launch_bounds__(256) void seq_kernel(const float* __restrict__ inputs,
                                                  float* __restrict__ s0) {
  int i = blockIdx.x * 256 + threadIdx.x;
  if (i >= HALF) return;
  uint32_t x0 = (uint32_t)i, x1 = (uint32_t)(i + HALF);
  threefry_0_42(x0, x1);
  s0[i]        = inputs[i]        + 0.01f * bits_to_normal(x0);
  s0[i + HALF] = inputs[i + HALF] + 0.01f * bits_to_normal(x1);
}

DEVFN float sigmoidf_(float x) { return 1.0f / (1.0f + expf(-x)); }

// ---------------------------------------------------------------------------
// adj -> i8 digit planes, TILED: [ng=n>>4][mc][q][nr][j], 16 KB per n-group.
// Each thread handles 4 consecutive m (one dword per plane).
// ---------------------------------------------------------------------------
__global__ __launch_bounds__(256) void adjsplit_kernel(const float* __restrict__ adj,
                                                       char* __restrict__ d1,
                                                       char* __restrict__ d0) {
  int i = (blockIdx.x * 256 + threadIdx.x) * 4;
  int n = i >> 10, m = i & 1023;
  uint32_t p1 = 0, p0 = 0;
#pragma unroll
  for (int r = 0; r < 4; ++r) {
    int A = __float2int_rn(adj[(size_t)n * 1024 + m + r] * 16777216.0f);
    int a1 = (A + 128) >> 8;
    int a0 = A - (a1 << 8);
    p1 |= ((uint32_t)(uint8_t)(char)a1) << (8 * r);
    p0 |= ((uint32_t)(uint8_t)(char)a0) << (8 * r);
  }
  size_t adr = (size_t)(n >> 4) * 16384 + (size_t)(n & 15) * 16 + tiladdr(m);
  *reinterpret_cast<uint32_t*>(d1 + adr) = p1;
  *reinterpret_cast<uint32_t*>(d0 + adr) = p0;
}

// ---------------------------------------------------------------------------
// wprep: split + transpose all GEMM B-weights into [n][k] bf16 hi/lo planes
// ---------------------------------------------------------------------------
__global__ __launch_bounds__(256) void wprep_kernel(
    const float* __restrict__ WzF, const float* __restrict__ WrF, const float* __restrict__ WcF,
    const float* __restrict__ WzR, const float* __restrict__ WrR, const float* __restrict__ WcR,
    const float* __restrict__ Wp2, const float* __restrict__ Wd1, const float* __restrict__ Wd2,
    ushort_t* __restrict__ WH, ushort_t* __restrict__ WL)
{
  size_t i = (size_t)blockIdx.x * 256 + threadIdx.x;
  if (i >= WTOT) return;
  float v;
  if (i < WOFF_PC) {                          // PZ [d][l][n:128][k:128]
    int d = (i >> 15) & 1, l = (i >> 14) & 1, n = (i >> 7) & 127, k = i & 127;
    const float* W = (n < 64) ? (d ? WzR : WzF) : (d ? WrR : WrF);
    v = W[l * 8192 + k * 64 + (n & 63)];
  } else if (i < WOFF_P2) {                   // PC [d][l][n:64][k:128]
    size_t j = i - WOFF_PC;
    int d = (j >> 14) & 1, l = (j >> 13) & 1, n = (j >> 7) & 63, k = j & 127;
    const float* W = d ? WcR : WcF;
    v = W[l * 8192 + k * 64 + n];
  } else if (i < WOFF_D1) {                   // P2 [n:64][k:256]
    size_t j = i - WOFF_P2;
    int n = j >> 8, k = j & 255;
    v = Wp2[k * 64 + n];
  } else if (i < WOFF_D2) {                   // D1 [n:256][k:128]
    size_t j = i - WOFF_D1;
    int n = j >> 7, k = j & 127;
    v = Wd1[k * 256 + n];
  } else {                                    // D2 [n:64][k:256]
    size_t j = i - WOFF_D2;
    int n = j >> 8, k = j & 255;
    v = Wd2[k * 64 + n];
  }
  ushort_t h = f2bf_rne(v);
  WH[i] = h;
  WL[i] = f2bf_rne(v - bf2f(h));
}

// ---------------------------------------------------------------------------
// proj: X[m][64] = relu(s0*W0+s1*W1+bp1) @ Wp2 + bp2   (float output)
// ---------------------------------------------------------------------------
__global__ __launch_bounds__(256) void proj_mfma(
    const float* __restrict__ s0g, const float* __restrict__ s1g,
    const float* __restrict__ Wp1, const float* __restrict__ bp1,
    const float* __restrict__ bp2,
    const ushort_t* __restrict__ WH, const ushort_t* __restrict__ WL,
    float* __restrict__ X)
{
  __shared__ float W0[256], W1[256], Bb[256], SS0[256], SS1[256];
  const int tid = threadIdx.x;
  const int row0 = blockIdx.x * 256;
  W0[tid] = Wp1[tid];
  W1[tid] = Wp1[256 + tid];
  Bb[tid] = bp1[tid];
  SS0[tid] = s0g[row0 + tid];
  SS1[tid] = s1g[row0 + tid];
  __syncthreads();

  const int lane = tid & 63, wave = tid >> 6;
  const int lm = lane & 15, q8 = (lane >> 4) * 8;
  const ushort_t* P2H = WH + WOFF_P2;
  const ushort_t* P2L = WL + WOFF_P2;

  float sv0[4], sv1[4];
#pragma unroll
  for (int ti = 0; ti < 4; ++ti) {
    sv0[ti] = SS0[wave * 64 + ti * 16 + lm];
    sv1[ti] = SS1[wave * 64 + ti * 16 + lm];
  }

  f32x4 acc[4][4];
#pragma unroll
  for (int i = 0; i < 4; ++i)
#pragma unroll
    for (int j = 0; j < 4; ++j) acc[i][j] = (f32x4)0.0f;

  for (int kt = 0; kt < 8; ++kt) {
    const int kc = kt * 32 + q8;
    bf16x8 bh[4], bl[4];
#pragma unroll
    for (int tj = 0; tj < 4; ++tj) {
      bh[tj] = ld16(P2H + (size_t)(tj * 16 + lm) * 256 + kc);
      bl[tj] = ld16(P2L + (size_t)(tj * 16 + lm) * 256 + kc);
    }
    float w08[8], w18[8], bb8[8];
#pragma unroll
    for (int j = 0; j < 8; ++j) { w08[j] = W0[kc + j]; w18[j] = W1[kc + j]; bb8[j] = Bb[kc + j]; }
#pragma unroll
    for (int ti = 0; ti < 4; ++ti) {
      float a8[8];
#pragma unroll
      for (int j = 0; j < 8; ++j)
        a8[j] = fmaxf(fmaf(sv0[ti], w08[j], fmaf(sv1[ti], w18[j], bb8[j])), 0.0f);
      bf16x8 ah, al;
      split8(a8, ah, al);
#pragma unroll
      for (int tj = 0; tj < 4; ++tj) acc[ti][tj] = mm3(ah, al, bh[tj], bl[tj], acc[ti][tj]);
    }
  }

  const int rq = (lane >> 4) * 4;
  const int rowbase = row0 + wave * 64;
#pragma unroll
  for (int ti = 0; ti < 4; ++ti)
#pragma unroll
    for (int tj = 0; tj < 4; ++tj) {
      const int col = tj * 16 + lm;
      const float bv = bp2[col];
#pragma unroll
      for (int r = 0; r < 4; ++r)
        X[(size_t)(rowbase + ti * 16 + rq + r) * 64 + col] = acc[ti][tj][r] + bv;
    }
}

// ---------------------------------------------------------------------------
// prez: G1t[dir][b] tiled i8 digit planes (8 fg x 16 KB) = T(xh @ [Wz|Wr])
// ---------------------------------------------------------------------------
__global__ __launch_bounds__(256) void prez_mfma(
    const float* __restrict__ x0p, const float* __restrict__ x1p,
    const float* __restrict__ h0p, const float* __restrict__ h1p,
    const ushort_t* __restrict__ WH, const ushort_t* __restrict__ WL,
    int l,
    char* __restrict__ G1t1, char* __restrict__ G1t0)
{
  __shared__ float T[128][132];
  const int tid = threadIdx.x;
  const int row0 = blockIdx.x * 128;
  const int dir  = blockIdx.z;
  const int b    = row0 >> 10;
  const int nloc = row0 & 1023;
  const float* __restrict__ xs = dir ? x1p : x0p;
  const float* __restrict__ hs = dir ? h1p : h0p;
  const ushort_t* BH = WH + WOFF_PZ + (size_t)(dir * 2 + l) * 16384;
  const ushort_t* BL = WL + WOFF_PZ + (size_t)(dir * 2 + l) * 16384;

  const int lane = tid & 63, wave = tid >> 6;
  const int wr = (wave >> 1) * 64, wc = (wave & 1) * 64;
  const int lm = lane & 15, q8 = (lane >> 4) * 8;

  f32x4 acc[4][4];
#pragma unroll
  for (int i = 0; i < 4; ++i)
#pragma unroll
    for (int j = 0; j < 4; ++j) acc[i][j] = (f32x4)0.0f;

#pragma unroll
  for (int kt = 0; kt < 4; ++kt) {
    const int k0 = kt * 32 + q8;
    bf16x8 bh[4], bl[4];
#pragma unroll
    for (int tj = 0; tj < 4; ++tj) {
      const size_t off = (size_t)(wc + tj * 16 + lm) * 128 + k0;
      bh[tj] = ld16(BH + off);
      bl[tj] = ld16(BL + off);
    }
#pragma unroll
    for (int ti = 0; ti < 4; ++ti) {
      const int row = row0 + wr + ti * 16 + lm;
      const float* src = (k0 < 64) ? (xs + (size_t)row * 64 + k0)
                                   : (hs + (size_t)row * 64 + (k0 - 64));
      float a8[8];
      ld8f(src, a8);
      bf16x8 ah, al;
      split8(a8, ah, al);
#pragma unroll
      for (int tj = 0; tj < 4; ++tj) acc[ti][tj] = mm3(ah, al, bh[tj], bl[tj], acc[ti][tj]);
    }
  }

  const int rq = (lane >> 4) * 4;
#pragma unroll
  for (int ti = 0; ti < 4; ++ti)
#pragma unroll
    for (int tj = 0; tj < 4; ++tj)
#pragma unroll
      for (int r = 0; r < 4; ++r)
        T[wc + tj * 16 + lm][wr + ti * 16 + rq + r] = acc[ti][tj][r];
  __syncthreads();

  {
    const int c = tid >> 1, mc = (tid & 1) * 64;
    const size_t pb = ((size_t)(dir * 16 + b) * 8 + (c >> 4)) * 16384 + (size_t)(c & 15) * 16;
#pragma unroll
    for (int q = 0; q < 4; ++q) {
      alignas(16) char q1[16], q0[16];
#pragma unroll
      for (int k = 0; k < 16; ++k)
        quant_i8(T[c][mc + q * 16 + k], q1[k], q0[k]);
      const int m16 = nloc + mc + q * 16;
      const size_t adr = pb + (size_t)(m16 >> 6) * 1024 + (size_t)((m16 >> 4) & 3) * 256;
      *reinterpret_cast<uint4*>(G1t1 + adr) = *reinterpret_cast<uint4*>(q1);
      *reinterpret_cast<uint4*>(G1t0 + adr) = *reinterpret_cast<uint4*>(q0);
    }
  }
}

// ---------------------------------------------------------------------------
// prec: G2t[b] tiled i8 digit planes (8 fg: dir*4 + c>>4) = T([x|r*h] @ Wc)
// ---------------------------------------------------------------------------
__global__ __launch_bounds__(128) void prec_mfma(
    const float* __restrict__ x0p, const float* __restrict__ x1p,
    const float* __restrict__ rhbuf,
    const ushort_t* __restrict__ WH, const ushort_t* __restrict__ WL,
    int l,
    char* __restrict__ G2t1, char* __restrict__ G2t0)
{
  __shared__ float T[64][132];
  const int tid = threadIdx.x;
  const int row0 = blockIdx.x * 128;
  const int dir  = blockIdx.z;
  const int b    = row0 >> 10;
  const int nloc = row0 & 1023;
  const float* __restrict__ xs = dir ? x1p : x0p;
  const float* __restrict__ rs = rhbuf + (size_t)dir * ((size_t)ROWS * 64);
  const ushort_t* BH = WH + WOFF_PC + (size_t)(dir * 2 + l) * 8192;
  const ushort_t* BL = WL + WOFF_PC + (size_t)(dir * 2 + l) * 8192;

  const int lane = tid & 63, wave = tid >> 6;   // wave 0..1
  const int wr = wave * 64;
  const int lm = lane & 15, q8 = (lane >> 4) * 8;

  f32x4 acc[4][4];
#pragma unroll
  for (int i = 0; i < 4; ++i)
#pragma unroll
    for (int j = 0; j < 4; ++j) acc[i][j] = (f32x4)0.0f;

#pragma unroll
  for (int kt = 0; kt < 4; ++kt) {
    const int k0 = kt * 32 + q8;
    bf16x8 bh[4], bl[4];
#pragma unroll
    for (int tj = 0; tj < 4; ++tj) {
      const size_t off = (size_t)(tj * 16 + lm) * 128 + k0;
      bh[tj] = ld16(BH + off);
      bl[tj] = ld16(BL + off);
    }
#pragma unroll
    for (int ti = 0; ti < 4; ++ti) {
      const int row = row0 + wr + ti * 16 + lm;
      const float* src = (k0 < 64) ? (xs + (size_t)row * 64 + k0)
                                   : (rs + (size_t)row * 64 + (k0 - 64));
      float a8[8];
      ld8f(src, a8);
      bf16x8 ah, al;
      split8(a8, ah, al);
#pragma unroll
      for (int tj = 0; tj < 4; ++tj) acc[ti][tj] = mm3(ah, al, bh[tj], bl[tj], acc[ti][tj]);
    }
  }

  const int rq = (lane >> 4) * 4;
#pragma unroll
  for (int ti = 0; ti < 4; ++ti)
#pragma unroll
    for (int tj = 0; tj < 4; ++tj)
#pragma unroll
      for (int r = 0; r < 4; ++r)
        T[tj * 16 + lm][wr + ti * 16 + rq + r] = acc[ti][tj][r];
  __syncthreads();

  {
    const int c = tid >> 1, mc = (tid & 1) * 64;
    const size_t pb = ((size_t)b * 8 + dir * 4 + (c >> 4)) * 16384 + (size_t)(c & 15) * 16;
#pragma unroll
    for (int q = 0; q < 4; ++q) {
      alignas(16) char q1[16], q0[16];
#pragma unroll
      for (int k = 0; k < 16; ++k)
        quant_i8(T[c][mc + q * 16 + k], q1[k], q0[k]);
      const int m16 = nloc + mc + q * 16;
      const size_t adr = pb + (size_t)(m16 >> 6) * 1024 + (size_t)((m16 >> 4) & 3) * 256;
      *reinterpret_cast<uint4*>(G2t1 + adr) = *reinterpret_cast<uint4*>(q1);
      *reinterpret_cast<uint4*>(G2t0 + adr) = *reinterpret_cast<uint4*>(q0);
    }
  }
}

// ---------------------------------------------------------------------------
// conv_mfma (i8 fixed point, tiled planes, fully-contiguous 1KB DMA):
// result = acc1*2^-20 + accm*2^-28.
// EPI=0: tile 128n x 64c, grid (16=b, 8=nt, 4=dir*2+gate)
// EPI=1: tile 128n x 32c, grid (16=b, 8=nt, 4=dir*2+colhalf)
// 256 thr, LDS double-buffered.
// ---------------------------------------------------------------------------
template<int EPI>
__global__ __launch_bounds__(256) void conv_mfma(
    const char* __restrict__ adj1, const char* __restrict__ adj0,
    const char* __restrict__ Bt1,  const char* __restrict__ Bt0,
    const float* __restrict__ c0F, const float* __restrict__ c0R,
    const float* __restrict__ c1F, const float* __restrict__ c1R,
    float* __restrict__ zbuf, float* __restrict__ rhb,
    float* __restrict__ h0, float* __restrict__ h1)
{
  constexpr int TI = 4;
  constexpr int TJ = (EPI == 0) ? 2 : 1;
  constexpr int NBG = (EPI == 0) ? 4 : 2;
  constexpr int BOFF_LDS = 16384;
  constexpr int BUFSZ = BOFF_LDS + NBG * 1024 * 2;

  __shared__ __align__(16) char LB[2][BUFSZ];

  const int tid = threadIdx.x;
  const int b   = blockIdx.x;
  const int n0  = blockIdx.y * 128;
  const int z   = blockIdx.z;
  const int dir = z >> 1, sel = z & 1;
  const int lane = tid & 63, wave = tid >> 6;

  // A staging: groups wave, wave+4 for both digit planes (tiled: +16KB/group)
  const char* sA1a = adj1 + ((size_t)(n0 >> 4) + wave) * 16384 + lane * 16;
  const char* sA1b = adj1 + ((size_t)(n0 >> 4) + wave + 4) * 16384 + lane * 16;
  const char* sA0a = adj0 + ((size_t)(n0 >> 4) + wave) * 16384 + lane * 16;
  const char* sA0b = adj0 + ((size_t)(n0 >> 4) + wave + 4) * 16384 + lane * 16;
  const int dA1a = wave * 1024 + lane * 16;
  const int dA1b = (wave + 4) * 1024 + lane * 16;
  const int dA0a = 8192 + dA1a;
  const int dA0b = 8192 + dA1b;

  const char* sB1 = nullptr; int dB1 = 0;
  const char* sB0 = nullptr; int dB0 = 0;
  if (EPI == 0) {
    const size_t pg = ((size_t)(dir * 16 + b) * 8 + sel * 4 + wave) * 16384;
    sB1 = Bt1 + pg + lane * 16;
    dB1 = BOFF_LDS + wave * 1024 + lane * 16;
    sB0 = Bt0 + pg + lane * 16;
    dB0 = BOFF_LDS + 4096 + wave * 1024 + lane * 16;
  } else {
    const int g = wave & 1;
    const size_t pg = ((size_t)b * 8 + dir * 4 + sel * 2 + g) * 16384;
    sB1 = ((wave < 2) ? Bt1 : Bt0) + pg + lane * 16;
    dB1 = BOFF_LDS + (wave < 2 ? 0 : 2048) + g * 1024 + lane * 16;
  }

  const int wr = (wave >> 1) * 64;
  const int wc = (EPI == 0) ? (wave & 1) * 32 : (wave & 1) * 16;

  i32x4 acc1[TI][TJ], accm[TI][TJ];
#pragma unroll
  for (int i = 0; i < TI; ++i)
#pragma unroll
    for (int j = 0; j < TJ; ++j) { acc1[i][j] = (i32x4)0; accm[i][j] = (i32x4)0; }

#define STAGE(bufi, kt)                                    \
  {                                                        \
    const int _o = (kt) * 1024;                            \
    char* _L = LB[bufi];                                   \
    async16(sA1a + _o, _L + dA1a);                         \
    async16(sA1b + _o, _L + dA1b);                         \
    async16(sA0a + _o, _L + dA0a);                         \
    async16(sA0b + _o, _L + dA0b);                         \
    async16(sB1 + _o, _L + dB1);                           \
    if (EPI == 0) async16(sB0 + _o, _L + dB0);             \
  }

  STAGE(0, 0)
  for (int kt = 0; kt < 16; ++kt) {
    __syncthreads();
    if (kt + 1 < 16) STAGE((kt + 1) & 1, kt + 1)
    const char* L = LB[kt & 1];

    i32x4 b1f[TJ], b0f[TJ];
#pragma unroll
    for (int tj = 0; tj < TJ; ++tj) {
      const int o = BOFF_LDS + ((wc + tj * 16) >> 4) * 1024 + lane * 16;
      b1f[tj] = *reinterpret_cast<const i32x4*>(L + o);
      b0f[tj] = *reinterpret_cast<const i32x4*>(L + o + NBG * 1024);
    }
#pragma unroll
    for (int ti = 0; ti < TI; ++ti) {
      const int o = ((wr + ti * 16) >> 4) * 1024 + lane * 16;
      i32x4 a1 = *reinterpret_cast<const i32x4*>(L + o);
      i32x4 a0 = *reinterpret_cast<const i32x4*>(L + 8192 + o);
#pragma unroll
      for (int tj = 0; tj < TJ; ++tj) {
        acc1[ti][tj] = __builtin_amdgcn_mfma_i32_16x16x64_i8(a1, b1f[tj], acc1[ti][tj], 0, 0, 0);
        accm[ti][tj] = __builtin_amdgcn_mfma_i32_16x16x64_i8(a1, b0f[tj], accm[ti][tj], 0, 0, 0);
        accm[ti][tj] = __builtin_amdgcn_mfma_i32_16x16x64_i8(a0, b1f[tj], accm[ti][tj], 0, 0, 0);
      }
    }
  }
#undef STAGE

  const int lm = lane & 15;
  const int rq = (lane >> 4) * 4;
  const size_t rowbase = (size_t)b * 1024 + n0 + wr;
  const float S1 = 0x1p-20f, Sm = 0x1p-28f;

  if (EPI == 0) {
    float* zb = zbuf + (size_t)dir * ((size_t)ROWS * 64);
    float* rb = rhb  + (size_t)dir * ((size_t)ROWS * 64);
    const float* hb = dir ? h1 : h0;
    if (sel == 0) {                      // z gate
      const float* bz = dir ? c0R : c0F;
#pragma unroll
      for (int ti = 0; ti < TI; ++ti)
#pragma unroll
        for (int tj = 0; tj < TJ; ++tj) {
          const int c = wc + tj * 16 + lm;
          const float bv = bz[c];
#pragma unroll
          for (int r = 0; r < 4; ++r) {
            const size_t row = rowbase + ti * 16 + rq + r;
            const float v = (float)acc1[ti][tj][r] * S1 + (float)accm[ti][tj][r] * Sm + bv;
            zb[row * 64 + c] = sigmoidf_(v);
          }
        }
    } else {                             // r gate -> rh
      const float* br = dir ? c1R : c1F;
#pragma unroll
      for (int ti = 0; ti < TI; ++ti)
#pragma unroll
        for (int tj = 0; tj < TJ; ++tj) {
          const int c = wc + tj * 16 + lm;
          const float bv = br[c];
#pragma unroll
          for (int r = 0; r < 4; ++r) {
            const size_t row = rowbase + ti * 16 + rq + r;
            const float v = (float)acc1[ti][tj][r] * S1 + (float)accm[ti][tj][r] * Sm + bv;
            rb[row * 64 + c] = sigmoidf_(v) * hb[row * 64 + c];
          }
        }
    }
  } else {
    const float* bc = dir ? c0R : c0F;
    const float* zb = zbuf + (size_t)dir * ((size_t)ROWS * 64);
    float* hb = dir ? h1 : h0;
#pragma unroll
    for (int ti = 0; ti < TI; ++ti)
#pragma unroll
      for (int tj = 0; tj < TJ; ++tj) {
        const int c = sel * 32 + wc + tj * 16 + lm;
        const float bv = bc[c];
#pragma unroll
        for (int r = 0; r < 4; ++r) {
          const size_t row = rowbase + ti * 16 + rq + r;
          const size_t idx = row * 64 + c;
          const float v = (float)acc1[ti][tj][r] * S1 + (float)accm[ti][tj][r] * Sm + bv;
          const float cc = tanhf(v);
          const float zv = zb[idx];
          const float hv = hb[idx];
          hb[idx] = zv * hv + (1.0f - zv) * cc;
        }
      }
  }
}

// ---------------------------------------------------------------------------
// dec1: D1[row][256] = relu(concat(hid_f,hid_r)[row] @ Wd1 + bd1)
// ---------------------------------------------------------------------------
__global__ __launch_bounds__(256) void dec1_mfma(
    const float* __restrict__ Hws,
    const ushort_t* __restrict__ WH, const ushort_t* __restrict__ WL,
    const float* __restrict__ bd1,
    float* __restrict__ D1)
{
  const int tid = threadIdx.x;
  const int row0 = blockIdx.x * 128;
  const int cb   = blockIdx.y * 128;
  const int l  = row0 >> 14;
  const int ri0 = row0 & 16383;
  const float* Hf = Hws + (size_t)l * HSZ;
  const float* Hr = Hws + (size_t)(2 + l) * HSZ;
  const ushort_t* BH = WH + WOFF_D1;
  const ushort_t* BL = WL + WOFF_D1;

  const int lane = tid & 63, wave = tid >> 6;
  const int wr = (wave >> 1) * 64, wc = (wave & 1) * 64;
  const int lm = lane & 15, q8 = (lane >> 4) * 8;

  f32x4 acc[4][4];
#pragma unroll
  for (int i = 0; i < 4; ++i)
#pragma unroll
    for (int j = 0; j < 4; ++j) acc[i][j] = (f32x4)0.0f;

#pragma unroll
  for (int kt = 0; kt < 4; ++kt) {
    const int k0 = kt * 32 + q8;
    bf16x8 bh[4], bl[4];
#pragma unroll
    for (int tj = 0; tj < 4; ++tj) {
      const size_t off = (size_t)(cb + wc + tj * 16 + lm) * 128 + k0;
      bh[tj] = ld16(BH + off);
      bl[tj] = ld16(BL + off);
    }
#pragma unroll
    for (int ti = 0; ti < 4; ++ti) {
      const int ri = ri0 + wr + ti * 16 + lm;
      const float* src = (k0 < 64) ? (Hf + (size_t)ri * 64 + k0)
                                   : (Hr + (size_t)ri * 64 + (k0 - 64));
      float a8[8];
      ld8f(src, a8);
      bf16x8 ah, al;
      split8(a8, ah, al);
#pragma unroll
      for (int tj = 0; tj < 4; ++tj) acc[ti][tj] = mm3(ah, al, bh[tj], bl[tj], acc[ti][tj]);
    }
  }

  const int rq = (lane >> 4) * 4;
#pragma unroll
  for (int ti = 0; ti < 4; ++ti)
#pragma unroll
    for (int tj = 0; tj < 4; ++tj) {
      const int col = cb + wc + tj * 16 + lm;
      const float bv = bd1[col];
#pragma unroll
      for (int r = 0; r < 4; ++r) {
        const size_t row = row0 + wr + ti * 16 + rq + r;
        D1[row * 256 + col] = fmaxf(acc[ti][tj][r] + bv, 0.0f);
      }
    }
}

// ---------------------------------------------------------------------------
// dec2: out[row][64] = D1[row] @ Wd2 + bd2
// ---------------------------------------------------------------------------
__global__ __launch_bounds__(256) void dec2_mfma(
    const float* __restrict__ D1,
    const ushort_t* __restrict__ WH, const ushort_t* __restrict__ WL,
    const float* __restrict__ bd2,
    float* __restrict__ out)
{
  const int tid = threadIdx.x;
  const int row0 = blockIdx.x * 256;
  const ushort_t* BH = WH + WOFF_D2;
  const ushort_t* BL = WL + WOFF_D2;

  const int lane = tid & 63, wave = tid >> 6;
  const int wr = wave * 64;
  const int lm = lane & 15, q8 = (lane >> 4) * 8;

  f32x4 acc[4][4];
#pragma unroll
  for (int i = 0; i < 4; ++i)
#pragma unroll
    for (int j = 0; j < 4; ++j) acc[i][j] = (f32x4)0.0f;

#pragma unroll
  for (int kt = 0; kt < 8; ++kt) {
    const int k0 = kt * 32 + q8;
    bf16x8 bh[4], bl[4];
#pragma unroll
    for (int tj = 0; tj < 4; ++tj) {
      const size_t off = (size_t)(tj * 16 + lm) * 256 + k0;
      bh[tj] = ld16(BH + off);
      bl[tj] = ld16(BL + off);
    }
#pragma unroll
    for (int ti = 0; ti < 4; ++ti) {
      const size_t row = row0 + wr + ti * 16 + lm;
      float a8[8];
      ld8f(D1 + row * 256 + k0, a8);
      bf16x8 ah, al;
      split8(a8, ah, al);
#pragma unroll
      for (int tj = 0; tj < 4; ++tj) acc[ti][tj] = mm3(ah, al, bh[tj], bl[tj], acc[ti][tj]);
    }
  }

  const int rq = (lane >> 4) * 4;
#pragma unroll
  for (int ti = 0; ti < 4; ++ti)
#pragma unroll
    for (int tj = 0; tj < 4; ++tj) {
      const int col = tj * 16 + lm;
      const float bv = bd2[col];
#pragma unroll
      for (int r = 0; r < 4; ++r) {
        const size_t row = row0 + wr + ti * 16 + rq + r;
        out[row * 64 + col] = acc[ti][tj][r] + bv;
      }
    }
}

// ---------------------------------------------------------------------------
// Host driver
// ---------------------------------------------------------------------------
extern "C" void kernel_launch(void* const* d_in, const int* in_sizes, int n_in,
                              void* d_out, int out_size, void* d_ws, size_t ws_size,
                              hipStream_t stream)
{
  (void)in_sizes; (void)n_in; (void)out_size; (void)ws_size;
  const float* inputs = (const float*)d_in[0];
  const float* mask   = (const float*)d_in[1];
  const float* adj    = (const float*)d_in[2];
  const float* Wp1    = (const float*)d_in[3];
  const float* bp1    = (const float*)d_in[4];
  const float* Wp2    = (const float*)d_in[5];
  const float* bp2    = (const float*)d_in[6];
  const float* Wz_f   = (const float*)d_in[7];
  const float* Wr_f   = (const float*)d_in[8];
  const float* Wc_f   = (const float*)d_in[9];
  const float* bz_f   = (const float*)d_in[10];
  const float* br_f   = (const float*)d_in[11];
  const float* bc_f   = (const float*)d_in[12];
  const float* Wz_r   = (const float*)d_in[13];
  const float* Wr_r   = (const float*)d_in[14];
  const float* Wc_r   = (const float*)d_in[15];
  const float* bz_r   = (const float*)d_in[16];
  const float* br_r   = (const float*)d_in[17];
  const float* bc_r   = (const float*)d_in[18];
  const float* Wd1    = (const float*)d_in[19];
  const float* bd1    = (const float*)d_in[20];
  const float* Wd2    = (const float*)d_in[21];
  const float* bd2    = (const float*)d_in[22];

  float* ws = (float*)d_ws;
  float* S0 = ws;                                   // TOT
  float* X  = S0 + TOT;                             // TOT*64
  float* H  = X + (size_t)TOT * 64;                 // 4*HSZ [dir*2+l]
  float* Z  = H + 4 * HSZ;                          // 2*HSZ
  float* RH = Z + 2 * HSZ;                          // 2*HSZ
  char* ADJ1 = (char*)(RH + 2 * HSZ);               // 1 MB tiled
  char* ADJ0 = ADJ1 + MB;                           // 1 MB tiled
  ushort_t* WH = (ushort_t*)(ADJ0 + MB);
  ushort_t* WL = WH + WTOT;
  char* U = (char*)(WL + WTOT);
  char* G1T1 = U;                                   // 4 MB tiled [dir*16+b][8fg]
  char* G1T0 = G1T1 + (size_t)4 * MB;               // 4 MB
  char* G2T1 = G1T0 + (size_t)4 * MB;               // 2 MB tiled [b][8fg]
  char* G2T0 = G2T1 + (size_t)2 * MB;               // 2 MB
  float* D1 = (float*)U;                            // 32 MB alias (post-loop)

  hipMemsetAsync(H, 0, 4 * HSZ * sizeof(float), stream);

  seq_kernel<<<dim3((HALF + 255) / 256), 256, 0, stream>>>(inputs, S0);
  wprep_kernel<<<dim3((int)((WTOT + 255) / 256)), 256, 0, stream>>>(
      Wz_f, Wr_f, Wc_f, Wz_r, Wr_r, Wc_r, Wp2, Wd1, Wd2, WH, WL);
  adjsplit_kernel<<<dim3(1024), 256, 0, stream>>>(adj, ADJ1, ADJ0);
  proj_mfma<<<dim3(TOT / 256), 256, 0, stream>>>(S0, mask, Wp1, bp1, bp2, WH, WL, X);

  for (int t = 0; t < Tn; ++t) {
    for (int l = 0; l < Ln; ++l) {
      const float* x0 = (l == 0) ? (X + (size_t)t * HSZ) : H;
      const float* x1 = (l == 0) ? (X + (size_t)(Tn - 1 - t) * HSZ) : (H + 2 * HSZ);
      float* h0 = H + (size_t)l * HSZ;
      float* h1 = H + (size_t)(2 + l) * HSZ;

      prez_mfma<<<dim3(128, 1, 2), 256, 0, stream>>>(
          x0, x1, h0, h1, WH, WL, l, G1T1, G1T0);
      conv_mfma<0><<<dim3(16, 8, 4), 256, 0, stream>>>(
          ADJ1, ADJ0, G1T1, G1T0,
          bz_f + l * 64, bz_r + l * 64, br_f + l * 64, br_r + l * 64,
          Z, RH, h0, h1);
      prec_mfma<<<dim3(128, 1, 2), 128, 0, stream>>>(
          x0, x1, RH, WH, WL, l, G2T1, G2T0);
      conv_mfma<1><<<dim3(16, 8, 4), 256, 0, stream>>>(
          ADJ1, ADJ0, G2T1, G2T0,
          bc_f + l * 64, bc_r + l * 64, bc_f + l * 64, bc_r + l * 64,
          Z, RH, h0, h1);
    }
  }

  dec1_mfma<<<dim3(256, 2), 256, 0, stream>>>(H, WH, WL, bd1, D1);
  dec2_mfma<<<dim3(128), 256, 0, stream>>>(D1, WH, WL, bd2, (float*)d_out);
}

// Round 12
// 1537.362 us; speedup vs baseline: 1.6131x; 1.0325x over previous
//
#include <hip/hip_runtime.h>
#include <cstdint>
#include <cstddef>

constexpr int Tn = 12, Bn = 16, Nn = 1024, Hn = 64, Ln = 2;
constexpr int ROWS = Bn * Nn;                 // 16384
constexpr int TOT  = Tn * Bn * Nn;            // 196608
constexpr int HALF = TOT / 2;
constexpr size_t HSZ = (size_t)Bn * Nn * Hn;  // 1048576 floats
constexpr size_t MB = 1048576;

#define DEVFN __device__ __forceinline__

typedef __attribute__((ext_vector_type(4))) float f32x4;
typedef __attribute__((ext_vector_type(4))) int   i32x4;
typedef __attribute__((ext_vector_type(8))) __bf16 bf16x8;
typedef unsigned short ushort_t;

// weight-plane offsets (elements) inside WH/WL (bf16 hi/lo)
constexpr size_t WOFF_PZ = 0;        // [d][l][n:128][k:128]  prez B
constexpr size_t WOFF_PC = 65536;    // [d][l][n:64][k:128]   prec B
constexpr size_t WOFF_P2 = 98304;    // [n:64][k:256]         Wp2
constexpr size_t WOFF_D1 = 114688;   // [n:256][k:128]        Wd1
constexpr size_t WOFF_D2 = 147456;   // [n:64][k:256]         Wd2
constexpr size_t WTOT    = 163840;

// ---------------------------------------------------------------------------
DEVFN ushort_t f2bf_rne(float f) {
  uint32_t u = __float_as_uint(f);
  uint32_t r = u + 0x7FFFu + ((u >> 16) & 1u);
  return (ushort_t)(r >> 16);
}
DEVFN float bf2f(ushort_t h) { return __uint_as_float(((uint32_t)h) << 16); }

DEVFN void split8(const float* f, bf16x8& h8, bf16x8& l8) {
  alignas(16) ushort_t hs[8], ls[8];
#pragma unroll
  for (int j = 0; j < 8; ++j) {
    ushort_t h = f2bf_rne(f[j]);
    hs[j] = h;
    ls[j] = f2bf_rne(f[j] - bf2f(h));
  }
  h8 = *reinterpret_cast<bf16x8*>(hs);
  l8 = *reinterpret_cast<bf16x8*>(ls);
}

DEVFN f32x4 mm3(bf16x8 ah, bf16x8 al, bf16x8 bh, bf16x8 bl, f32x4 c) {
  c = __builtin_amdgcn_mfma_f32_16x16x32_bf16(ah, bh, c, 0, 0, 0);
  c = __builtin_amdgcn_mfma_f32_16x16x32_bf16(ah, bl, c, 0, 0, 0);
  c = __builtin_amdgcn_mfma_f32_16x16x32_bf16(al, bh, c, 0, 0, 0);
  return c;
}

DEVFN bf16x8 ld16(const ushort_t* p) { return *reinterpret_cast<const bf16x8*>(p); }

DEVFN void ld8f(const float* p, float* out) {
  float4 v0 = *reinterpret_cast<const float4*>(p);
  float4 v1 = *reinterpret_cast<const float4*>(p + 4);
  out[0] = v0.x; out[1] = v0.y; out[2] = v0.z; out[3] = v0.w;
  out[4] = v1.x; out[5] = v1.y; out[6] = v1.z; out[7] = v1.w;
}

DEVFN void async16(const void* g, void* l) {
  __builtin_amdgcn_global_load_lds(
      (const __attribute__((address_space(1))) uint32_t*)g,
      (__attribute__((address_space(3))) uint32_t*)l, 16, 0, 0);
}

// i8 fixed point digits, scale 2^-12
DEVFN void quant_i8(float v, char& b1, char& b0) {
  int i = __float2int_rn(v * 4096.0f);
  i = max(-32768, min(32639, i));
  int d1 = (i + 128) >> 8;
  int d0 = i - (d1 << 8);
  b1 = (char)d1; b0 = (char)d0;
}

// tiled i8 plane addressing within a 16-row group (16 KB):
//   addr = (m>>6)*1024 + ((m>>4)&3)*256 + (row&15)*16 + (m&15)
DEVFN size_t tiladdr(int m) { return (size_t)(m >> 6) * 1024 + (size_t)((m >> 4) & 3) * 256 + (m & 15); }

// ---------------------------------------------------------------------------
// threefry2x32 (key 0,42) + XLA-exact normal
// ---------------------------------------------------------------------------
DEVFN uint32_t rotl32(uint32_t v, int d) { return (v << d) | (v >> (32 - d)); }

DEVFN void threefry_0_42(uint32_t& x0, uint32_t& x1) {
  const uint32_t k0 = 0u, k1 = 42u, k2 = k0 ^ k1 ^ 0x1BD11BDAu;
  x0 += k0; x1 += k1;
#define TFR(r) { x0 += x1; x1 = rotl32(x1, r); x1 ^= x0; }
  TFR(13) TFR(15) TFR(26) TFR(6)
  x0 += k1; x1 += k2 + 1u;
  TFR(17) TFR(29) TFR(16) TFR(24)
  x0 += k2; x1 += k0 + 2u;
  TFR(13) TFR(15) TFR(26) TFR(6)
  x0 += k0; x1 += k1 + 3u;
  TFR(17) TFR(29) TFR(16) TFR(24)
  x0 += k1; x1 += k2 + 4u;
  TFR(13) TFR(15) TFR(26) TFR(6)
  x0 += k2; x1 += k0 + 5u;
#undef TFR
}

DEVFN float erfinv32(float x) {
  float w = -log1pf(-x * x);
  float p;
  if (w < 5.0f) {
    w = w - 2.5f;
    p = 2.81022636e-08f;
    p = fmaf(p, w, 3.43273939e-07f);
    p = fmaf(p, w, -3.5233877e-06f);
    p = fmaf(p, w, -4.39150654e-06f);
    p = fmaf(p, w, 0.00021858087f);
    p = fmaf(p, w, -0.00125372503f);
    p = fmaf(p, w, -0.00417768164f);
    p = fmaf(p, w, 0.246640727f);
    p = fmaf(p, w, 1.50140941f);
  } else {
    w = sqrtf(w) - 3.0f;
    p = -0.000200214257f;
    p = fmaf(p, w, 0.000100950558f);
    p = fmaf(p, w, 0.00134934322f);
    p = fmaf(p, w, -0.00367342844f);
    p = fmaf(p, w, 0.00573950773f);
    p = fmaf(p, w, -0.0076224613f);
    p = fmaf(p, w, 0.00943887047f);
    p = fmaf(p, w, 1.00167406f);
    p = fmaf(p, w, 2.83297682f);
  }
  return p * x;
}

DEVFN float bits_to_normal(uint32_t bits) {
  float f = __uint_as_float((bits >> 9) | 0x3f800000u) - 1.0f;
  const float lo = -0.99999994f;
  float u = fmaf(f, 2.0f, lo);
  u = fmaxf(lo, u);
  return 1.41421356237f * erfinv32(u);
}

__global__ __launch_bounds__(256) void seq_kernel(const float* __restrict__ inputs,
                                                  float* __restrict__ s0) {
  int i = blockIdx.x * 256 + threadIdx.x;
  if (i >= HALF) return;
  uint32_t x0 = (uint32_t)i, x1 = (uint32_t)(i + HALF);
  threefry_0_42(x0, x1);
  s0[i]        = inputs[i]        + 0.01f * bits_to_normal(x0);
  s0[i + HALF] = inputs[i + HALF] + 0.01f * bits_to_normal(x1);
}

DEVFN float sigmoidf_(float x) { return 1.0f / (1.0f + expf(-x)); }

// ---------------------------------------------------------------------------
// adj -> i8 digit planes, TILED
// ---------------------------------------------------------------------------
__global__ __launch_bounds__(256) void adjsplit_kernel(const float* __restrict__ adj,
                                                       char* __restrict__ d1,
                                                       char* __restrict__ d0) {
  int i = (blockIdx.x * 256 + threadIdx.x) * 4;
  int n = i >> 10, m = i & 1023;
  uint32_t p1 = 0, p0 = 0;
#pragma unroll
  for (int r = 0; r < 4; ++r) {
    int A = __float2int_rn(adj[(size_t)n * 1024 + m + r] * 16777216.0f);
    int a1 = (A + 128) >> 8;
    int a0 = A - (a1 << 8);
    p1 |= ((uint32_t)(uint8_t)(char)a1) << (8 * r);
    p0 |= ((uint32_t)(uint8_t)(char)a0) << (8 * r);
  }
  size_t adr = (size_t)(n >> 4) * 16384 + (size_t)(n & 15) * 16 + tiladdr(m);
  *reinterpret_cast<uint32_t*>(d1 + adr) = p1;
  *reinterpret_cast<uint32_t*>(d0 + adr) = p0;
}

// ---------------------------------------------------------------------------
// wprep: split + transpose all GEMM B-weights into [n][k] bf16 hi/lo planes
// ---------------------------------------------------------------------------
__global__ __launch_bounds__(256) void wprep_kernel(
    const float* __restrict__ WzF, const float* __restrict__ WrF, const float* __restrict__ WcF,
    const float* __restrict__ WzR, const float* __restrict__ WrR, const float* __restrict__ WcR,
    const float* __restrict__ Wp2, const float* __restrict__ Wd1, const float* __restrict__ Wd2,
    ushort_t* __restrict__ WH, ushort_t* __restrict__ WL)
{
  size_t i = (size_t)blockIdx.x * 256 + threadIdx.x;
  if (i >= WTOT) return;
  float v;
  if (i < WOFF_PC) {                          // PZ [d][l][n:128][k:128]
    int d = (i >> 15) & 1, l = (i >> 14) & 1, n = (i >> 7) & 127, k = i & 127;
    const float* W = (n < 64) ? (d ? WzR : WzF) : (d ? WrR : WrF);
    v = W[l * 8192 + k * 64 + (n & 63)];
  } else if (i < WOFF_P2) {                   // PC [d][l][n:64][k:128]
    size_t j = i - WOFF_PC;
    int d = (j >> 14) & 1, l = (j >> 13) & 1, n = (j >> 7) & 63, k = j & 127;
    const float* W = d ? WcR : WcF;
    v = W[l * 8192 + k * 64 + n];
  } else if (i < WOFF_D1) {                   // P2 [n:64][k:256]
    size_t j = i - WOFF_P2;
    int n = j >> 8, k = j & 255;
    v = Wp2[k * 64 + n];
  } else if (i < WOFF_D2) {                   // D1 [n:256][k:128]
    size_t j = i - WOFF_D1;
    int n = j >> 7, k = j & 127;
    v = Wd1[k * 256 + n];
  } else {                                    // D2 [n:64][k:256]
    size_t j = i - WOFF_D2;
    int n = j >> 8, k = j & 255;
    v = Wd2[k * 64 + n];
  }
  ushort_t h = f2bf_rne(v);
  WH[i] = h;
  WL[i] = f2bf_rne(v - bf2f(h));
}

// ---------------------------------------------------------------------------
// proj: X[m][64] = relu(s0*W0+s1*W1+bp1) @ Wp2 + bp2   (float output)
// ---------------------------------------------------------------------------
__global__ __launch_bounds__(256) void proj_mfma(
    const float* __restrict__ s0g, const float* __restrict__ s1g,
    const float* __restrict__ Wp1, const float* __restrict__ bp1,
    const float* __restrict__ bp2,
    const ushort_t* __restrict__ WH, const ushort_t* __restrict__ WL,
    float* __restrict__ X)
{
  __shared__ float W0[256], W1[256], Bb[256], SS0[256], SS1[256];
  const int tid = threadIdx.x;
  const int row0 = blockIdx.x * 256;
  W0[tid] = Wp1[tid];
  W1[tid] = Wp1[256 + tid];
  Bb[tid] = bp1[tid];
  SS0[tid] = s0g[row0 + tid];
  SS1[tid] = s1g[row0 + tid];
  __syncthreads();

  const int lane = tid & 63, wave = tid >> 6;
  const int lm = lane & 15, q8 = (lane >> 4) * 8;
  const ushort_t* P2H = WH + WOFF_P2;
  const ushort_t* P2L = WL + WOFF_P2;

  float sv0[4], sv1[4];
#pragma unroll
  for (int ti = 0; ti < 4; ++ti) {
    sv0[ti] = SS0[wave * 64 + ti * 16 + lm];
    sv1[ti] = SS1[wave * 64 + ti * 16 + lm];
  }

  f32x4 acc[4][4];
#pragma unroll
  for (int i = 0; i < 4; ++i)
#pragma unroll
    for (int j = 0; j < 4; ++j) acc[i][j] = (f32x4)0.0f;

  for (int kt = 0; kt < 8; ++kt) {
    const int kc = kt * 32 + q8;
    bf16x8 bh[4], bl[4];
#pragma unroll
    for (int tj = 0; tj < 4; ++tj) {
      bh[tj] = ld16(P2H + (size_t)(tj * 16 + lm) * 256 + kc);
      bl[tj] = ld16(P2L + (size_t)(tj * 16 + lm) * 256 + kc);
    }
    float w08[8], w18[8], bb8[8];
#pragma unroll
    for (int j = 0; j < 8; ++j) { w08[j] = W0[kc + j]; w18[j] = W1[kc + j]; bb8[j] = Bb[kc + j]; }
#pragma unroll
    for (int ti = 0; ti < 4; ++ti) {
      float a8[8];
#pragma unroll
      for (int j = 0; j < 8; ++j)
        a8[j] = fmaxf(fmaf(sv0[ti], w08[j], fmaf(sv1[ti], w18[j], bb8[j])), 0.0f);
      bf16x8 ah, al;
      split8(a8, ah, al);
#pragma unroll
      for (int tj = 0; tj < 4; ++tj) acc[ti][tj] = mm3(ah, al, bh[tj], bl[tj], acc[ti][tj]);
    }
  }

  const int rq = (lane >> 4) * 4;
  const int rowbase = row0 + wave * 64;
#pragma unroll
  for (int ti = 0; ti < 4; ++ti)
#pragma unroll
    for (int tj = 0; tj < 4; ++tj) {
      const int col = tj * 16 + lm;
      const float bv = bp2[col];
#pragma unroll
      for (int r = 0; r < 4; ++r)
        X[(size_t)(rowbase + ti * 16 + rq + r) * 64 + col] = acc[ti][tj][r] + bv;
    }
}

// ---------------------------------------------------------------------------
// prez: G1t[dir][b] tiled i8 digit planes = T(xh @ [Wz|Wr]); 64-row tiles
// grid (256,1,2) = 512 blocks (2/CU)
// ---------------------------------------------------------------------------
__global__ __launch_bounds__(256) void prez_mfma(
    const float* __restrict__ x0p, const float* __restrict__ x1p,
    const float* __restrict__ h0p, const float* __restrict__ h1p,
    const ushort_t* __restrict__ WH, const ushort_t* __restrict__ WL,
    int l,
    char* __restrict__ G1t1, char* __restrict__ G1t0)
{
  __shared__ float T[128][68];
  const int tid = threadIdx.x;
  const int row0 = blockIdx.x * 64;
  const int dir  = blockIdx.z;
  const int b    = row0 >> 10;
  const int nloc = row0 & 1023;
  const float* __restrict__ xs = dir ? x1p : x0p;
  const float* __restrict__ hs = dir ? h1p : h0p;
  const ushort_t* BH = WH + WOFF_PZ + (size_t)(dir * 2 + l) * 16384;
  const ushort_t* BL = WL + WOFF_PZ + (size_t)(dir * 2 + l) * 16384;

  const int lane = tid & 63, wave = tid >> 6;
  const int wr = (wave >> 1) * 32, wc = (wave & 1) * 64;
  const int lm = lane & 15, q8 = (lane >> 4) * 8;

  f32x4 acc[2][4];
#pragma unroll
  for (int i = 0; i < 2; ++i)
#pragma unroll
    for (int j = 0; j < 4; ++j) acc[i][j] = (f32x4)0.0f;

#pragma unroll
  for (int kt = 0; kt < 4; ++kt) {
    const int k0 = kt * 32 + q8;
    bf16x8 bh[4], bl[4];
#pragma unroll
    for (int tj = 0; tj < 4; ++tj) {
      const size_t off = (size_t)(wc + tj * 16 + lm) * 128 + k0;
      bh[tj] = ld16(BH + off);
      bl[tj] = ld16(BL + off);
    }
#pragma unroll
    for (int ti = 0; ti < 2; ++ti) {
      const int row = row0 + wr + ti * 16 + lm;
      const float* src = (k0 < 64) ? (xs + (size_t)row * 64 + k0)
                                   : (hs + (size_t)row * 64 + (k0 - 64));
      float a8[8];
      ld8f(src, a8);
      bf16x8 ah, al;
      split8(a8, ah, al);
#pragma unroll
      for (int tj = 0; tj < 4; ++tj) acc[ti][tj] = mm3(ah, al, bh[tj], bl[tj], acc[ti][tj]);
    }
  }

  const int rq = (lane >> 4) * 4;
#pragma unroll
  for (int ti = 0; ti < 2; ++ti)
#pragma unroll
    for (int tj = 0; tj < 4; ++tj)
#pragma unroll
      for (int r = 0; r < 4; ++r)
        T[wc + tj * 16 + lm][wr + ti * 16 + rq + r] = acc[ti][tj][r];
  __syncthreads();

  {
    const int c = tid >> 1, mh = (tid & 1) * 32;
    const size_t pb = ((size_t)(dir * 16 + b) * 8 + (c >> 4)) * 16384 + (size_t)(c & 15) * 16;
#pragma unroll
    for (int q = 0; q < 2; ++q) {
      alignas(16) char q1[16], q0[16];
#pragma unroll
      for (int k = 0; k < 16; ++k)
        quant_i8(T[c][mh + q * 16 + k], q1[k], q0[k]);
      const int m16 = nloc + mh + q * 16;
      const size_t adr = pb + (size_t)(m16 >> 6) * 1024 + (size_t)((m16 >> 4) & 3) * 256;
      *reinterpret_cast<uint4*>(G1t1 + adr) = *reinterpret_cast<uint4*>(q1);
      *reinterpret_cast<uint4*>(G1t0 + adr) = *reinterpret_cast<uint4*>(q0);
    }
  }
}

// ---------------------------------------------------------------------------
// prec: G2t[b] tiled i8 digit planes = T([x|r*h] @ Wc)   (128-row tiles)
// ---------------------------------------------------------------------------
__global__ __launch_bounds__(128) void prec_mfma(
    const float* __restrict__ x0p, const float* __restrict__ x1p,
    const float* __restrict__ rhbuf,
    const ushort_t* __restrict__ WH, const ushort_t* __restrict__ WL,
    int l,
    char* __restrict__ G2t1, char* __restrict__ G2t0)
{
  __shared__ float T[64][132];           // stride 132: rows 0..127 (FIXED vs R11)
  const int tid = threadIdx.x;
  const int row0 = blockIdx.x * 128;
  const int dir  = blockIdx.z;
  const int b    = row0 >> 10;
  const int nloc = row0 & 1023;
  const float* __restrict__ xs = dir ? x1p : x0p;
  const float* __restrict__ rs = rhbuf + (size_t)dir * ((size_t)ROWS * 64);
  const ushort_t* BH = WH + WOFF_PC + (size_t)(dir * 2 + l) * 8192;
  const ushort_t* BL = WL + WOFF_PC + (size_t)(dir * 2 + l) * 8192;

  const int lane = tid & 63, wave = tid >> 6;   // wave 0..1
  const int wr = wave * 64;
  const int lm = lane & 15, q8 = (lane >> 4) * 8;

  f32x4 acc[4][4];
#pragma unroll
  for (int i = 0; i < 4; ++i)
#pragma unroll
    for (int j = 0; j < 4; ++j) acc[i][j] = (f32x4)0.0f;

#pragma unroll
  for (int kt = 0; kt < 4; ++kt) {
    const int k0 = kt * 32 + q8;
    bf16x8 bh[4], bl[4];
#pragma unroll
    for (int tj = 0; tj < 4; ++tj) {
      const size_t off = (size_t)(tj * 16 + lm) * 128 + k0;
      bh[tj] = ld16(BH + off);
      bl[tj] = ld16(BL + off);
    }
#pragma unroll
    for (int ti = 0; ti < 4; ++ti) {
      const int row = row0 + wr + ti * 16 + lm;
      const float* src = (k0 < 64) ? (xs + (size_t)row * 64 + k0)
                                   : (rs + (size_t)row * 64 + (k0 - 64));
      float a8[8];
      ld8f(src, a8);
      bf16x8 ah, al;
      split8(a8, ah, al);
#pragma unroll
      for (int tj = 0; tj < 4; ++tj) acc[ti][tj] = mm3(ah, al, bh[tj], bl[tj], acc[ti][tj]);
    }
  }

  const int rq = (lane >> 4) * 4;
#pragma unroll
  for (int ti = 0; ti < 4; ++ti)
#pragma unroll
    for (int tj = 0; tj < 4; ++tj)
#pragma unroll
      for (int r = 0; r < 4; ++r)
        T[tj * 16 + lm][wr + ti * 16 + rq + r] = acc[ti][tj][r];
  __syncthreads();

  {
    const int c = tid >> 1, mc = (tid & 1) * 64;
    const size_t pb = ((size_t)b * 8 + dir * 4 + (c >> 4)) * 16384 + (size_t)(c & 15) * 16;
#pragma unroll
    for (int q = 0; q < 4; ++q) {
      alignas(16) char q1[16], q0[16];
#pragma unroll
      for (int k = 0; k < 16; ++k)
        quant_i8(T[c][mc + q * 16 + k], q1[k], q0[k]);
      const int m16 = nloc + mc + q * 16;
      const size_t adr = pb + (size_t)(m16 >> 6) * 1024 + (size_t)((m16 >> 4) & 3) * 256;
      *reinterpret_cast<uint4*>(G2t1 + adr) = *reinterpret_cast<uint4*>(q1);
      *reinterpret_cast<uint4*>(G2t0 + adr) = *reinterpret_cast<uint4*>(q0);
    }
  }
}

// ---------------------------------------------------------------------------
// conv_mfma (i8 fixed point, tiled planes, 1KB DMA streams):
// result = acc1*2^-20 + accm*2^-28.
// EPI=0: tile 64n x 64c, grid (16=b, 16=nt, 4=dir*2+gate)  -> 1024 blocks
// EPI=1: tile 64n x 32c, grid (16=b, 16=nt, 4=dir*2+colhalf)
// 256 thr, LDS dbuf (32 KB / 24 KB) -> ~4 blocks/CU for latency hiding.
// ---------------------------------------------------------------------------
template<int EPI>
__global__ __launch_bounds__(256) void conv_mfma(
    const char* __restrict__ adj1, const char* __restrict__ adj0,
    const char* __restrict__ Bt1,  const char* __restrict__ Bt0,
    const float* __restrict__ c0F, const float* __restrict__ c0R,
    const float* __restrict__ c1F, const float* __restrict__ c1R,
    float* __restrict__ zbuf, float* __restrict__ rhb,
    float* __restrict__ h0, float* __restrict__ h1)
{
  constexpr int TI = 2;
  constexpr int TJ = (EPI == 0) ? 2 : 1;
  constexpr int NBG = (EPI == 0) ? 4 : 2;          // B col groups
  constexpr int NTR = 8 + 2 * NBG;                 // transfers per iter
  constexpr int PW = NTR / 4;                      // per wave
  constexpr int BOFF = 8192;                       // A region: 4 groups x 2 planes
  constexpr int BUFSZ = BOFF + NBG * 2048;

  __shared__ __align__(16) char LB[2][BUFSZ];

  const int tid = threadIdx.x;
  const int b   = blockIdx.x;
  const int n0  = blockIdx.y * 64;
  const int z   = blockIdx.z;
  const int dir = z >> 1, sel = z & 1;
  const int lane = tid & 63, wave = tid >> 6;

  // transfer table: i = wave + 4*j
  const char* tsrc[PW];
  int tdst[PW];
#pragma unroll
  for (int j = 0; j < PW; ++j) {
    const int i = wave + j * 4;
    const char* src; int dst;
    if (i < 4) {                 // A1 groups 0..3
      src = adj1 + ((size_t)(n0 >> 4) + i) * 16384;
      dst = i * 1024;
    } else if (i < 8) {          // A0 groups 0..3
      const int g = i - 4;
      src = adj0 + ((size_t)(n0 >> 4) + g) * 16384;
      dst = 4096 + g * 1024;
    } else if (i < 8 + NBG) {    // B1 groups
      const int g = i - 8;
      const size_t pg = (EPI == 0)
          ? ((size_t)(dir * 16 + b) * 8 + sel * 4 + g) * 16384
          : ((size_t)b * 8 + dir * 4 + sel * 2 + g) * 16384;
      src = Bt1 + pg;
      dst = BOFF + g * 1024;
    } else {                     // B0 groups
      const int g = i - 8 - NBG;
      const size_t pg = (EPI == 0)
          ? ((size_t)(dir * 16 + b) * 8 + sel * 4 + g) * 16384
          : ((size_t)b * 8 + dir * 4 + sel * 2 + g) * 16384;
      src = Bt0 + pg;
      dst = BOFF + NBG * 1024 + g * 1024;
    }
    tsrc[j] = src + lane * 16;
    tdst[j] = dst + lane * 16;
  }

  const int wr = (wave >> 1) * 32;
  const int wc = (EPI == 0) ? (wave & 1) * 32 : (wave & 1) * 16;

  i32x4 acc1[TI][TJ], accm[TI][TJ];
#pragma unroll
  for (int i = 0; i < TI; ++i)
#pragma unroll
    for (int j = 0; j < TJ; ++j) { acc1[i][j] = (i32x4)0; accm[i][j] = (i32x4)0; }

#define STAGE(bufi, kt)                                    \
  {                                                        \
    char* _L = LB[bufi];                                   \
    _Pragma("unroll")                                      \
    for (int j = 0; j < PW; ++j)                           \
      async16(tsrc[j] + (kt) * 1024, _L + tdst[j]);        \
  }

  STAGE(0, 0)
  for (int kt = 0; kt < 16; ++kt) {
    __syncthreads();
    if (kt + 1 < 16) STAGE((kt + 1) & 1, kt + 1)
    const char* L = LB[kt & 1];

    i32x4 b1f[TJ], b0f[TJ];
#pragma unroll
    for (int tj = 0; tj < TJ; ++tj) {
      const int o = BOFF + ((wc + tj * 16) >> 4) * 1024 + lane * 16;
      b1f[tj] = *reinterpret_cast<const i32x4*>(L + o);
      b0f[tj] = *reinterpret_cast<const i32x4*>(L + o + NBG * 1024);
    }
#pragma unroll
    for (int ti = 0; ti < TI; ++ti) {
      const int o = ((wr + ti * 16) >> 4) * 1024 + lane * 16;
      i32x4 a1 = *reinterpret_cast<const i32x4*>(L + o);
      i32x4 a0 = *reinterpret_cast<const i32x4*>(L + 4096 + o);
#pragma unroll
      for (int tj = 0; tj < TJ; ++tj) {
        acc1[ti][tj] = __builtin_amdgcn_mfma_i32_16x16x64_i8(a1, b1f[tj], acc1[ti][tj], 0, 0, 0);
        accm[ti][tj] = __builtin_amdgcn_mfma_i32_16x16x64_i8(a1, b0f[tj], accm[ti][tj], 0, 0, 0);
        accm[ti][tj] = __builtin_amdgcn_mfma_i32_16x16x64_i8(a0, b1f[tj], accm[ti][tj], 0, 0, 0);
      }
    }
  }
#undef STAGE

  const int lm = lane & 15;
  const int rq = (lane >> 4) * 4;
  const size_t rowbase = (size_t)b * 1024 + n0 + wr;
  const float S1 = 0x1p-20f, Sm = 0x1p-28f;

  if (EPI == 0) {
    float* zb = zbuf + (size_t)dir * ((size_t)ROWS * 64);
    float* rb = rhb  + (size_t)dir * ((size_t)ROWS * 64);
    const float* hb = dir ? h1 : h0;
    if (sel == 0) {                      // z gate
      const float* bz = dir ? c0R : c0F;
#pragma unroll
      for (int ti = 0; ti < TI; ++ti)
#pragma unroll
        for (int tj = 0; tj < TJ; ++tj) {
          const int c = wc + tj * 16 + lm;
          const float bv = bz[c];
#pragma unroll
          for (int r = 0; r < 4; ++r) {
            const size_t row = rowbase + ti * 16 + rq + r;
            const float v = (float)acc1[ti][tj][r] * S1 + (float)accm[ti][tj][r] * Sm + bv;
            zb[row * 64 + c] = sigmoidf_(v);
          }
        }
    } else {                             // r gate -> rh
      const float* br = dir ? c1R : c1F;
#pragma unroll
      for (int ti = 0; ti < TI; ++ti)
#pragma unroll
        for (int tj = 0; tj < TJ; ++tj) {
          const int c = wc + tj * 16 + lm;
          const float bv = br[c];
#pragma unroll
          for (int r = 0; r < 4; ++r) {
            const size_t row = rowbase + ti * 16 + rq + r;
            const float v = (float)acc1[ti][tj][r] * S1 + (float)accm[ti][tj][r] * Sm + bv;
            rb[row * 64 + c] = sigmoidf_(v) * hb[row * 64 + c];
          }
        }
    }
  } else {
    const float* bc = dir ? c0R : c0F;
    const float* zb = zbuf + (size_t)dir * ((size_t)ROWS * 64);
    float* hb = dir ? h1 : h0;
#pragma unroll
    for (int ti = 0; ti < TI; ++ti)
#pragma unroll
      for (int tj = 0; tj < TJ; ++tj) {
        const int c = sel * 32 + wc + tj * 16 + lm;
        const float bv = bc[c];
#pragma unroll
        for (int r = 0; r < 4; ++r) {
          const size_t row = rowbase + ti * 16 + rq + r;
          const size_t idx = row * 64 + c;
          const float v = (float)acc1[ti][tj][r] * S1 + (float)accm[ti][tj][r] * Sm + bv;
          const float cc = tanhf(v);
          const float zv = zb[idx];
          const float hv = hb[idx];
          hb[idx] = zv * hv + (1.0f - zv) * cc;
        }
      }
  }
}

// ---------------------------------------------------------------------------
// dec1: D1[row][256] = relu(concat(hid_f,hid_r)[row] @ Wd1 + bd1)
// ---------------------------------------------------------------------------
__global__ __launch_bounds__(256) void dec1_mfma(
    const float* __restrict__ Hws,
    const ushort_t* __restrict__ WH, const ushort_t* __restrict__ WL,
    const float* __restrict__ bd1,
    float* __restrict__ D1)
{
  const int tid = threadIdx.x;
  const int row0 = blockIdx.x * 128;
  const int cb   = blockIdx.y * 128;
  const int l  = row0 >> 14;
  const int ri0 = row0 & 16383;
  const float* Hf = Hws + (size_t)l * HSZ;
  const float* Hr = Hws + (size_t)(2 + l) * HSZ;
  const ushort_t* BH = WH + WOFF_D1;
  const ushort_t* BL = WL + WOFF_D1;

  const int lane = tid & 63, wave = tid >> 6;
  const int wr = (wave >> 1) * 64, wc = (wave & 1) * 64;
  const int lm = lane & 15, q8 = (lane >> 4) * 8;

  f32x4 acc[4][4];
#pragma unroll
  for (int i = 0; i < 4; ++i)
#pragma unroll
    for (int j = 0; j < 4; ++j) acc[i][j] = (f32x4)0.0f;

#pragma unroll
  for (int kt = 0; kt < 4; ++kt) {
    const int k0 = kt * 32 + q8;
    bf16x8 bh[4], bl[4];
#pragma unroll
    for (int tj = 0; tj < 4; ++tj) {
      const size_t off = (size_t)(cb + wc + tj * 16 + lm) * 128 + k0;
      bh[tj] = ld16(BH + off);
      bl[tj] = ld16(BL + off);
    }
#pragma unroll
    for (int ti = 0; ti < 4; ++ti) {
      const int ri = ri0 + wr + ti * 16 + lm;
      const float* src = (k0 < 64) ? (Hf + (size_t)ri * 64 + k0)
                                   : (Hr + (size_t)ri * 64 + (k0 - 64));
      float a8[8];
      ld8f(src, a8);
      bf16x8 ah, al;
      split8(a8, ah, al);
#pragma unroll
      for (int tj = 0; tj < 4; ++tj) acc[ti][tj] = mm3(ah, al, bh[tj], bl[tj], acc[ti][tj]);
    }
  }

  const int rq = (lane >> 4) * 4;
#pragma unroll
  for (int ti = 0; ti < 4; ++ti)
#pragma unroll
    for (int tj = 0; tj < 4; ++tj) {
      const int col = cb + wc + tj * 16 + lm;
      const float bv = bd1[col];
#pragma unroll
      for (int r = 0; r < 4; ++r) {
        const size_t row = row0 + wr + ti * 16 + rq + r;
        D1[row * 256 + col] = fmaxf(acc[ti][tj][r] + bv, 0.0f);
      }
    }
}

// ---------------------------------------------------------------------------
// dec2: out[row][64] = D1[row] @ Wd2 + bd2
// ---------------------------------------------------------------------------
__global__ __launch_bounds__(256) void dec2_mfma(
    const float* __restrict__ D1,
    const ushort_t* __restrict__ WH, const ushort_t* __restrict__ WL,
    const float* __restrict__ bd2,
    float* __restrict__ out)
{
  const int tid = threadIdx.x;
  const int row0 = blockIdx.x * 256;
  const ushort_t* BH = WH + WOFF_D2;
  const ushort_t* BL = WL + WOFF_D2;

  const int lane = tid & 63, wave = tid >> 6;
  const int wr = wave * 64;
  const int lm = lane & 15, q8 = (lane >> 4) * 8;

  f32x4 acc[4][4];
#pragma unroll
  for (int i = 0; i < 4; ++i)
#pragma unroll
    for (int j = 0; j < 4; ++j) acc[i][j] = (f32x4)0.0f;

#pragma unroll
  for (int kt = 0; kt < 8; ++kt) {
    const int k0 = kt * 32 + q8;
    bf16x8 bh[4], bl[4];
#pragma unroll
    for (int tj = 0; tj < 4; ++tj) {
      const size_t off = (size_t)(tj * 16 + lm) * 256 + k0;
      bh[tj] = ld16(BH + off);
      bl[tj] = ld16(BL + off);
    }
#pragma unroll
    for (int ti = 0; ti < 4; ++ti) {
      const size_t row = row0 + wr + ti * 16 + lm;
      float a8[8];
      ld8f(D1 + row * 256 + k0, a8);
      bf16x8 ah, al;
      split8(a8, ah, al);
#pragma unroll
      for (int tj = 0; tj < 4; ++tj) acc[ti][tj] = mm3(ah, al, bh[tj], bl[tj], acc[ti][tj]);
    }
  }

  const int rq = (lane >> 4) * 4;
#pragma unroll
  for (int ti = 0; ti < 4; ++ti)
#pragma unroll
    for (int tj = 0; tj < 4; ++tj) {
      const int col = tj * 16 + lm;
      const float bv = bd2[col];
#pragma unroll
      for (int r = 0; r < 4; ++r) {
        const size_t row = row0 + wr + ti * 16 + rq + r;
        out[row * 64 + col] = acc[ti][tj][r] + bv;
      }
    }
}

// ---------------------------------------------------------------------------
// Host driver
// ---------------------------------------------------------------------------
extern "C" void kernel_launch(void* const* d_in, const int* in_sizes, int n_in,
                              void* d_out, int out_size, void* d_ws, size_t ws_size,
                              hipStream_t stream)
{
  (void)in_sizes; (void)n_in; (void)out_size; (void)ws_size;
  const float* inputs = (const float*)d_in[0];
  const float* mask   = (const float*)d_in[1];
  const float* adj    = (const float*)d_in[2];
  const float* Wp1    = (const float*)d_in[3];
  const float* bp1    = (const float*)d_in[4];
  const float* Wp2    = (const float*)d_in[5];
  const float* bp2    = (const float*)d_in[6];
  const float* Wz_f   = (const float*)d_in[7];
  const float* Wr_f   = (const float*)d_in[8];
  const float* Wc_f   = (const float*)d_in[9];
  const float* bz_f   = (const float*)d_in[10];
  const float* br_f   = (const float*)d_in[11];
  const float* bc_f   = (const float*)d_in[12];
  const float* Wz_r   = (const float*)d_in[13];
  const float* Wr_r   = (const float*)d_in[14];
  const float* Wc_r   = (const float*)d_in[15];
  const float* bz_r   = (const float*)d_in[16];
  const float* br_r   = (const float*)d_in[17];
  const float* bc_r   = (const float*)d_in[18];
  const float* Wd1    = (const float*)d_in[19];
  const float* bd1    = (const float*)d_in[20];
  const float* Wd2    = (const float*)d_in[21];
  const float* bd2    = (const float*)d_in[22];

  float* ws = (float*)d_ws;
  float* S0 = ws;                                   // TOT
  float* X  = S0 + TOT;                             // TOT*64
  float* H  = X + (size_t)TOT * 64;                 // 4*HSZ [dir*2+l]
  float* Z  = H + 4 * HSZ;                          // 2*HSZ
  float* RH = Z + 2 * HSZ;                          // 2*HSZ
  char* ADJ1 = (char*)(RH + 2 * HSZ);               // 1 MB tiled
  char* ADJ0 = ADJ1 + MB;                           // 1 MB tiled
  ushort_t* WH = (ushort_t*)(ADJ0 + MB);
  ushort_t* WL = WH + WTOT;
  char* U = (char*)(WL + WTOT);
  char* G1T1 = U;                                   // 4 MB tiled [dir*16+b][8fg]
  char* G1T0 = G1T1 + (size_t)4 * MB;               // 4 MB
  char* G2T1 = G1T0 + (size_t)4 * MB;               // 2 MB tiled [b][8fg]
  char* G2T0 = G2T1 + (size_t)2 * MB;               // 2 MB
  float* D1 = (float*)U;                            // 32 MB alias (post-loop)

  hipMemsetAsync(H, 0, 4 * HSZ * sizeof(float), stream);

  seq_kernel<<<dim3((HALF + 255) / 256), 256, 0, stream>>>(inputs, S0);
  wprep_kernel<<<dim3((int)((WTOT + 255) / 256)), 256, 0, stream>>>(
      Wz_f, Wr_f, Wc_f, Wz_r, Wr_r, Wc_r, Wp2, Wd1, Wd2, WH, WL);
  adjsplit_kernel<<<dim3(1024), 256, 0, stream>>>(adj, ADJ1, ADJ0);
  proj_mfma<<<dim3(TOT / 256), 256, 0, stream>>>(S0, mask, Wp1, bp1, bp2, WH, WL, X);

  for (int t = 0; t < Tn; ++t) {
    for (int l = 0; l < Ln; ++l) {
      const float* x0 = (l == 0) ? (X + (size_t)t * HSZ) : H;
      const float* x1 = (l == 0) ? (X + (size_t)(Tn - 1 - t) * HSZ) : (H + 2 * HSZ);
      float* h0 = H + (size_t)l * HSZ;
      float* h1 = H + (size_t)(2 + l) * HSZ;

      prez_mfma<<<dim3(256, 1, 2), 256, 0, stream>>>(
          x0, x1, h0, h1, WH, WL, l, G1T1, G1T0);
      conv_mfma<0><<<dim3(16, 16, 4), 256, 0, stream>>>(
          ADJ1, ADJ0, G1T1, G1T0,
          bz_f + l * 64, bz_r + l * 64, br_f + l * 64, br_r + l * 64,
          Z, RH, h0, h1);
      prec_mfma<<<dim3(128, 1, 2), 128, 0, stream>>>(
          x0, x1, RH, WH, WL, l, G2T1, G2T0);
      conv_mfma<1><<<dim3(16, 16, 4), 256, 0, stream>>>(
          ADJ1, ADJ0, G2T1, G2T0,
          bc_f + l * 64, bc_r + l * 64, bc_f + l * 64, bc_r + l * 64,
          Z, RH, h0, h1);
    }
  }

  dec1_mfma<<<dim3(256, 2), 256, 0, stream>>>(H, WH, WL, bd1, D1);
  dec2_mfma<<<dim3(128), 256, 0, stream>>>(D1, WH, WL, bd2, (float*)d_out);
}